// Round 4
// baseline (321.887 us; speedup 1.0000x reference)
//
#include <hip/hip_runtime.h>
#include <hip/hip_bf16.h>
#include <math.h>

#define N_K 5292
#define N_Q 1344
#define H_KV 384
#define NH_KD 128
#define OUT_DIM 512
#define NROWS 21504   // 2*8*1344 (b,h,q) rows of partials
#define LOG2E 1.4426950408889634f

typedef float f32x4 __attribute__((ext_vector_type(4)));
typedef short short8 __attribute__((ext_vector_type(8)));

__device__ __forceinline__ float fexp2(float x) {
#if __has_builtin(__builtin_amdgcn_exp2f)
    return __builtin_amdgcn_exp2f(x);
#else
    return exp2f(x);
#endif
}

// packed f32x2 -> bf16x2 (v_cvt_pk_bf16_f32 on gfx950); x in low 16 bits
__device__ __forceinline__ unsigned pk_bf16(float a, float b) {
    union { __hip_bfloat162 h; unsigned u; } c;
    c.h = __float22bfloat162_rn(make_float2(a, b));
    return c.u;
}

// fp32x4 -> bf16 hi + bf16 lo (residual), packed
__device__ __forceinline__ void hilo_pk(float4 v, uint2& hi, uint2& lo) {
    unsigned h0 = pk_bf16(v.x, v.y);
    unsigned h1 = pk_bf16(v.z, v.w);
    float hx = __uint_as_float(h0 << 16);
    float hy = __uint_as_float(h0 & 0xffff0000u);
    float hz = __uint_as_float(h1 << 16);
    float hw = __uint_as_float(h1 & 0xffff0000u);
    hi = make_uint2(h0, h1);
    lo = make_uint2(pk_bf16(v.x - hx, v.y - hy), pk_bf16(v.z - hz, v.w - hw));
}

// ---------------- zero scratch ----------------
__global__ void zero_f(float* __restrict__ p, int n) {
    int i = blockIdx.x * 256 + threadIdx.x;
    if (i < n) p[i] = 0.f;
}

// ---- MFMA GEMM: Y[m][n] = sum_k X[row(m)][k] * W[n][k], K=256, fused col stats ----
// bf16 hi/lo 3-term split for ~fp32 accuracy at MFMA rate. 64x64 tile, BK=32.
// A-frag: m=lane&15 (+16*w), k=(lane>>4)*8+j ; B-frag: n=lane&15 (+16*nt), same k.
// C/D: col(n)=lane&15, row(m within 16)=(lane>>4)*4+reg.
__global__ __launch_bounds__(256) void gemm_mfma(const float* __restrict__ X,
                                                 const float* __restrict__ W,
                                                 float* __restrict__ Y,
                                                 float* __restrict__ sums,
                                                 int M, int Ncols, int mode)
{
    __shared__ unsigned short As_h[64][40], As_l[64][40], Bs_h[64][40], Bs_l[64][40];
    const int t = threadIdx.x;
    const int w = t >> 6, lane = t & 63, g = lane >> 4, ln = lane & 15;
    const int m0 = blockIdx.y * 64, n0 = blockIdx.x * 64;

    const int srow = t >> 2;          // staged row 0..63
    const int sk   = (t & 3) * 8;     // k offset within chunk

    int mrow = m0 + srow;
    long xsrc = -1;
    if (mrow < M) {
        if (mode == 1) {
            int bb = mrow / N_Q;
            int i = mrow - bb * N_Q;
            xsrc = (long)(bb * N_K + (i / 42) * 168 + (i % 42) * 2);
        } else xsrc = mrow;
    }
    const int nrow = n0 + srow;       // Ncols is a multiple of 64

    f32x4 acc[4];
    #pragma unroll
    for (int nt = 0; nt < 4; ++nt) acc[nt] = (f32x4){0.f, 0.f, 0.f, 0.f};

    for (int k0 = 0; k0 < 256; k0 += 32) {
        float4 xa = make_float4(0.f, 0.f, 0.f, 0.f), xb = xa;
        if (xsrc >= 0) {
            xa = *(const float4*)(X + xsrc * 256 + k0 + sk);
            xb = *(const float4*)(X + xsrc * 256 + k0 + sk + 4);
        }
        float4 wa = *(const float4*)(W + (size_t)nrow * 256 + k0 + sk);
        float4 wb = *(const float4*)(W + (size_t)nrow * 256 + k0 + sk + 4);

        uint2 xah, xal, xbh, xbl, wah, wal, wbh, wbl;
        hilo_pk(xa, xah, xal); hilo_pk(xb, xbh, xbl);
        hilo_pk(wa, wah, wal); hilo_pk(wb, wbh, wbl);

        __syncthreads();
        *(uint4*)&As_h[srow][sk] = make_uint4(xah.x, xah.y, xbh.x, xbh.y);
        *(uint4*)&As_l[srow][sk] = make_uint4(xal.x, xal.y, xbl.x, xbl.y);
        *(uint4*)&Bs_h[srow][sk] = make_uint4(wah.x, wah.y, wbh.x, wbh.y);
        *(uint4*)&Bs_l[srow][sk] = make_uint4(wal.x, wal.y, wbl.x, wbl.y);
        __syncthreads();

        short8 ah = *(const short8*)&As_h[w * 16 + ln][g * 8];
        short8 al = *(const short8*)&As_l[w * 16 + ln][g * 8];
        #pragma unroll
        for (int nt = 0; nt < 4; ++nt) {
            short8 bh = *(const short8*)&Bs_h[nt * 16 + ln][g * 8];
            short8 bl = *(const short8*)&Bs_l[nt * 16 + ln][g * 8];
            acc[nt] = __builtin_amdgcn_mfma_f32_16x16x32_bf16(al, bh, acc[nt], 0, 0, 0);
            acc[nt] = __builtin_amdgcn_mfma_f32_16x16x32_bf16(ah, bl, acc[nt], 0, 0, 0);
            acc[nt] = __builtin_amdgcn_mfma_f32_16x16x32_bf16(ah, bh, acc[nt], 0, 0, 0);
        }
    }

    // store C
    #pragma unroll
    for (int nt = 0; nt < 4; ++nt) {
        #pragma unroll
        for (int reg = 0; reg < 4; ++reg) {
            int mr = m0 + w * 16 + g * 4 + reg;
            if (mr < M) Y[(size_t)mr * Ncols + n0 + nt * 16 + ln] = acc[nt][reg];
        }
    }

    // fused column stats: sum/sumsq over this block's 64 rows (OOB rows are zeros)
    float s4[4], q4[4];
    #pragma unroll
    for (int nt = 0; nt < 4; ++nt) {
        float s = acc[nt][0] + acc[nt][1] + acc[nt][2] + acc[nt][3];
        float q = fmaf(acc[nt][0], acc[nt][0], fmaf(acc[nt][1], acc[nt][1],
                  fmaf(acc[nt][2], acc[nt][2], acc[nt][3] * acc[nt][3])));
        s += __shfl_xor(s, 16); s += __shfl_xor(s, 32);   // reduce over g
        q += __shfl_xor(q, 16); q += __shfl_xor(q, 32);
        s4[nt] = s; q4[nt] = q;
    }
    __syncthreads();
    float* st_s = (float*)&As_h[0][0];       // 256 floats
    float* st_q = st_s + 256;                // 256 floats (fits in As_h: 5120 B)
    if (g == 0) {
        #pragma unroll
        for (int nt = 0; nt < 4; ++nt) {
            st_s[(w * 4 + nt) * 16 + ln] = s4[nt];
            st_q[(w * 4 + nt) * 16 + ln] = q4[nt];
        }
    }
    __syncthreads();
    if (t < 64) {
        int nt = t >> 4, c = t & 15;
        float a = 0.f, b2 = 0.f;
        #pragma unroll
        for (int ww = 0; ww < 4; ++ww) {
            a  += st_s[(ww * 4 + nt) * 16 + c];
            b2 += st_q[(ww * 4 + nt) * 16 + c];
        }
        atomicAdd(&sums[n0 + nt * 16 + c], a);
        atomicAdd(&sums[Ncols + n0 + nt * 16 + c], b2);
    }
}

// ---- BN coeffs for kv (384 cols) and q (128 cols, attention scale*log2e folded) ----
__global__ void bn_coeffs(const float* __restrict__ sums_kv, const float* __restrict__ sums_q,
                          const float* __restrict__ kv_g, const float* __restrict__ kv_b,
                          const float* __restrict__ q_g, const float* __restrict__ q_b,
                          float* __restrict__ kv_sc, float* __restrict__ kv_sh,
                          float* __restrict__ q_sc, float* __restrict__ q_sh)
{
    int c = blockIdx.x * 256 + threadIdx.x;
    if (c < 384) {
        float inv = 1.f / 10584.f;
        float mu  = sums_kv[c] * inv;
        float var = fmaf(-mu, mu, sums_kv[384 + c] * inv);
        float s   = kv_g[c] * rsqrtf(var + 1e-5f);
        kv_sc[c] = s;
        kv_sh[c] = fmaf(-mu, s, kv_b[c]);
    } else if (c < 512) {
        int cc = c - 384;
        float inv = 1.f / 2688.f;
        float post = 0.25f * LOG2E;
        float mu  = sums_q[cc] * inv;
        float var = fmaf(-mu, mu, sums_q[128 + cc] * inv);
        float s   = q_g[cc] * rsqrtf(var + 1e-5f) * post;
        q_sc[cc] = s;
        q_sh[cc] = fmaf(-mu, s, q_b[cc] * post);
    }
}

// ---- normalize (finalize BN inline): out = Y*scale + shift (for proj) ----
__global__ __launch_bounds__(256) void norm_apply(
    const float* __restrict__ Y, const float* __restrict__ sums,
    const float* __restrict__ g, const float* __restrict__ bb,
    float* __restrict__ out, int rows, int cols, float inv_rows)
{
    __shared__ float sc_s[64], sh_s[64];
    const int t = threadIdx.x;
    const int c0 = blockIdx.x * 64;
    if (t < 64) {
        int c = c0 + t;
        float mu  = sums[c] * inv_rows;
        float var = fmaf(-mu, mu, sums[cols + c] * inv_rows);
        float s   = g[c] * rsqrtf(var + 1e-5f);
        sc_s[t] = s;
        sh_s[t] = fmaf(-mu, s, bb[c]);
    }
    __syncthreads();
    const int c4 = (t & 15) * 4;
    float4 scv = *(const float4*)&sc_s[c4];
    float4 shv = *(const float4*)&sh_s[c4];
    for (int r = blockIdx.y * 16 + (t >> 4); r < rows; r += gridDim.y * 16) {
        size_t off = (size_t)r * cols + c0 + c4;
        float4 v = *(const float4*)(Y + off);
        v.x = fmaf(v.x, scv.x, shv.x);
        v.y = fmaf(v.y, scv.y, shv.y);
        v.z = fmaf(v.z, scv.z, shv.z);
        v.w = fmaf(v.w, scv.w, shv.w);
        *(float4*)(out + off) = v;
    }
}

// ---- bias remap: bt_r[h][dr*84+dc] = bias_table[h][rank] * log2e (f32) ----
__global__ void bias_remap(const float* __restrict__ bias_table, const int* __restrict__ bias_idxs,
                           float* __restrict__ bt_r, int n_off)
{
    int i = blockIdx.x * 256 + threadIdx.x;
    if (i < 8 * N_K) {
        int h = i / N_K, j = i - h * N_K;
        bt_r[i] = bias_table[h * n_off + bias_idxs[j]] * LOG2E;
    }
}

// ---- MFMA flash attention, 4-way key split, exp2-domain softmax ----
// grid (21 qtiles, 8 heads, 8 = b*4+ks). block 256 = 4 waves; wave w owns 16 q rows.
// Bias windowed: this ks-slice touches kr in [16ks,16ks+15] -> dr spans <=20 rows.
__global__ __launch_bounds__(256, 6) void attn_mfma(
    const float* __restrict__ kv_y, const float* __restrict__ q_y,
    const float* __restrict__ kv_sc, const float* __restrict__ kv_sh,
    const float* __restrict__ q_sc, const float* __restrict__ q_sh,
    const float* __restrict__ bt_r,
    float* __restrict__ pm, float* __restrict__ pl, float* __restrict__ pacc)
{
    const int qt = blockIdx.x, h = blockIdx.y;
    const int b = blockIdx.z >> 2, ks = blockIdx.z & 3;
    const int t = threadIdx.x;
    const int w = t >> 6, lane = t & 63, g = lane >> 4, ln = lane & 15;

    __shared__ float bt_s[21 * 84];            // 7056 B, f32 window
    __shared__ unsigned short K_s[64][24];     // 3072 B
    __shared__ unsigned short Vt_s[32][72];    // 4608 B
    __shared__ unsigned short P_s[4][16][72];  // 9216 B

    const int q0 = qt * 64;
    const int kstart = ks * 1344;
    const int kend = (kstart + 1344 < N_K) ? kstart + 1344 : N_K;

    // bias window rows
    const int kr0 = ks * 16;
    const int kr1 = (kend - 1) / 84;
    const int rq2min = (q0 / 42) * 2;
    const int rq2max = ((q0 + 63) / 42) * 2;
    int dr_lo = 0;
    if (rq2min > kr1) dr_lo = rq2min - kr1;
    else if (kr0 > rq2max) dr_lo = kr0 - rq2max;
    int a1 = rq2max - kr0, a2 = kr1 - rq2min;
    int dr_hi = a1 > a2 ? a1 : a2;
    {
        int nb = (dr_hi - dr_lo + 1) * 84;
        const float* src = bt_r + h * N_K + dr_lo * 84;
        for (int j = t; j < nb; j += 256) bt_s[j] = src[j];
    }

    // Q A-fragment (BN+scale applied, bf16); k=d<16 so lane groups 2,3 zero
    short8 qfrag = (short8)0;
    if (lane < 32) {
        const float* qp = q_y + (size_t)(b * N_Q + q0 + w * 16 + ln) * NH_KD + h * 16 + g * 8;
        float4 q0v = *(const float4*)qp;
        float4 q1v = *(const float4*)(qp + 4);
        const float* scp = q_sc + h * 16 + g * 8;
        const float* shp = q_sh + h * 16 + g * 8;
        q0v.x = fmaf(q0v.x, scp[0], shp[0]); q0v.y = fmaf(q0v.y, scp[1], shp[1]);
        q0v.z = fmaf(q0v.z, scp[2], shp[2]); q0v.w = fmaf(q0v.w, scp[3], shp[3]);
        q1v.x = fmaf(q1v.x, scp[4], shp[4]); q1v.y = fmaf(q1v.y, scp[5], shp[5]);
        q1v.z = fmaf(q1v.z, scp[6], shp[6]); q1v.w = fmaf(q1v.w, scp[7], shp[7]);
        union { short8 s; unsigned u[4]; } qf;
        qf.u[0] = pk_bf16(q0v.x, q0v.y); qf.u[1] = pk_bf16(q0v.z, q0v.w);
        qf.u[2] = pk_bf16(q1v.x, q1v.y); qf.u[3] = pk_bf16(q1v.z, q1v.w);
        qfrag = qf.s;
    }

    // per-reg query geometry
    int rq2[4], cq2[4];
    #pragma unroll
    for (int reg = 0; reg < 4; ++reg) {
        int qg = q0 + w * 16 + g * 4 + reg;
        rq2[reg] = (qg / 42) * 2;
        cq2[reg] = (qg % 42) * 2;
    }
    // per-subtile key geometry (incremental)
    int kr[4], kc[4];
    #pragma unroll
    for (int st = 0; st < 4; ++st) {
        int kg = kstart + st * 16 + ln;
        kr[st] = kg / 84;
        kc[st] = kg - kr[st] * 84;
    }

    // hoisted staging coefficients
    const int skk = t >> 2, skc = (t & 3) * 4;          // K stage: key, ch
    float4 k_sc = *(const float4*)(kv_sc + h * 48 + skc);
    float4 k_sh = *(const float4*)(kv_sh + h * 48 + skc);
    const int vkk = t & 63;                              // V stage key
    float4 v_sc0 = *(const float4*)(kv_sc + h * 48 + 16 + (t >> 6) * 4);
    float4 v_sh0 = *(const float4*)(kv_sh + h * 48 + 16 + (t >> 6) * 4);
    float4 v_sc1 = *(const float4*)(kv_sc + h * 48 + 32 + (t >> 6) * 4);
    float4 v_sh1 = *(const float4*)(kv_sh + h * 48 + 32 + (t >> 6) * 4);

    float m[4], l[4];
    #pragma unroll
    for (int r = 0; r < 4; ++r) { m[r] = -1e30f; l[r] = 0.f; }
    f32x4 acc0 = {0.f, 0.f, 0.f, 0.f}, acc1 = {0.f, 0.f, 0.f, 0.f};
    const f32x4 zero4 = {0.f, 0.f, 0.f, 0.f};

    for (int k0 = kstart; k0 < kend; k0 += 64) {
        __syncthreads();   // prior tile fragment reads done
        { // stage K: 64 keys x 16 d
            int kg = k0 + skk;
            float4 v = make_float4(0.f, 0.f, 0.f, 0.f);
            if (kg < N_K) {
                v = *(const float4*)(kv_y + (size_t)(b * N_K + kg) * H_KV + h * 48 + skc);
                v.x = fmaf(v.x, k_sc.x, k_sh.x); v.y = fmaf(v.y, k_sc.y, k_sh.y);
                v.z = fmaf(v.z, k_sc.z, k_sh.z); v.w = fmaf(v.w, k_sc.w, k_sh.w);
            }
            *(uint2*)&K_s[skk][skc] = make_uint2(pk_bf16(v.x, v.y), pk_bf16(v.z, v.w));
        }
        #pragma unroll
        for (int i = 0; i < 2; ++i) { // stage V transposed: Vt[v][key]
            int v4 = ((t >> 6) + i * 4) * 4;
            int kg = k0 + vkk;
            float4 sc = i ? v_sc1 : v_sc0, sh = i ? v_sh1 : v_sh0;
            float4 v = make_float4(0.f, 0.f, 0.f, 0.f);
            if (kg < N_K) {
                v = *(const float4*)(kv_y + (size_t)(b * N_K + kg) * H_KV + h * 48 + 16 + v4);
                v.x = fmaf(v.x, sc.x, sh.x); v.y = fmaf(v.y, sc.y, sh.y);
                v.z = fmaf(v.z, sc.z, sh.z); v.w = fmaf(v.w, sc.w, sh.w);
            }
            unsigned u0 = pk_bf16(v.x, v.y), u1 = pk_bf16(v.z, v.w);
            Vt_s[v4 + 0][vkk] = (unsigned short)u0;
            Vt_s[v4 + 1][vkk] = (unsigned short)(u0 >> 16);
            Vt_s[v4 + 2][vkk] = (unsigned short)u1;
            Vt_s[v4 + 3][vkk] = (unsigned short)(u1 >> 16);
        }
        __syncthreads();

        // QK^T
        f32x4 sf[4];
        #pragma unroll
        for (int st = 0; st < 4; ++st) {
            short8 bf = (short8)0;
            if (lane < 32) bf = *(const short8*)&K_s[st * 16 + ln][g * 8];
            sf[st] = __builtin_amdgcn_mfma_f32_16x16x32_bf16(qfrag, bf, zero4, 0, 0, 0);
        }

        // bias + mask + row max (log2 domain)
        float scv[4][4];
        float rmax[4] = {-1e30f, -1e30f, -1e30f, -1e30f};
        #pragma unroll
        for (int st = 0; st < 4; ++st) {
            bool valid = (k0 + st * 16 + ln) < N_K;
            #pragma unroll
            for (int reg = 0; reg < 4; ++reg) {
                int dr = rq2[reg] - kr[st]; dr = dr < 0 ? -dr : dr;
                int dc = cq2[reg] - kc[st]; dc = dc < 0 ? -dc : dc;
                float v = sf[st][reg] + bt_s[(dr - dr_lo) * 84 + dc];
                v = valid ? v : -1e30f;
                scv[st][reg] = v;
                rmax[reg] = fmaxf(rmax[reg], v);
            }
        }
        #pragma unroll
        for (int reg = 0; reg < 4; ++reg) {
            float r = rmax[reg];
            r = fmaxf(r, __shfl_xor(r, 1, 16));
            r = fmaxf(r, __shfl_xor(r, 2, 16));
            r = fmaxf(r, __shfl_xor(r, 4, 16));
            r = fmaxf(r, __shfl_xor(r, 8, 16));
            rmax[reg] = r;
        }

        // online update + P -> LDS (packed bf16 converts)
        #pragma unroll
        for (int reg = 0; reg < 4; ++reg) {
            float mn = fmaxf(m[reg], rmax[reg]);
            float alpha = fexp2(m[reg] - mn);
            m[reg] = mn;
            l[reg] *= alpha;
            acc0[reg] *= alpha;
            acc1[reg] *= alpha;
            float p0 = fexp2(scv[0][reg] - mn);
            float p1 = fexp2(scv[1][reg] - mn);
            float p2 = fexp2(scv[2][reg] - mn);
            float p3 = fexp2(scv[3][reg] - mn);
            l[reg] += (p0 + p1) + (p2 + p3);
            unsigned u01 = pk_bf16(p0, p1), u23 = pk_bf16(p2, p3);
            P_s[w][g * 4 + reg][ln]      = (unsigned short)u01;
            P_s[w][g * 4 + reg][16 + ln] = (unsigned short)(u01 >> 16);
            P_s[w][g * 4 + reg][32 + ln] = (unsigned short)u23;
            P_s[w][g * 4 + reg][48 + ln] = (unsigned short)(u23 >> 16);
        }

        // PV (per-wave P_s; lgkmcnt orders the RAW)
        #pragma unroll
        for (int kt = 0; kt < 2; ++kt) {
            short8 af = *(const short8*)&P_s[w][ln][g * 8 + kt * 32];
            short8 b0 = *(const short8*)&Vt_s[ln][g * 8 + kt * 32];
            short8 b1 = *(const short8*)&Vt_s[ln + 16][g * 8 + kt * 32];
            acc0 = __builtin_amdgcn_mfma_f32_16x16x32_bf16(af, b0, acc0, 0, 0, 0);
            acc1 = __builtin_amdgcn_mfma_f32_16x16x32_bf16(af, b1, acc1, 0, 0, 0);
        }

        // advance key geometry
        #pragma unroll
        for (int st = 0; st < 4; ++st) {
            kc[st] += 64;
            if (kc[st] >= 84) { kc[st] -= 84; kr[st] += 1; }
        }
    }

    // row-sum of l
    #pragma unroll
    for (int reg = 0; reg < 4; ++reg) {
        float s = l[reg];
        s += __shfl_xor(s, 1, 16);
        s += __shfl_xor(s, 2, 16);
        s += __shfl_xor(s, 4, 16);
        s += __shfl_xor(s, 8, 16);
        l[reg] = s;
    }

    const int rbase = (b * 8 + h) * N_Q + q0 + w * 16;
    #pragma unroll
    for (int reg = 0; reg < 4; ++reg) {
        int prow = ks * NROWS + rbase + g * 4 + reg;
        pacc[(size_t)prow * 32 + ln]      = acc0[reg];
        pacc[(size_t)prow * 32 + 16 + ln] = acc1[reg];
        if (ln == 0) { pm[prow] = m[reg]; pl[prow] = l[reg]; }
    }
}

// ---- combine 4 key-split partials (exp2 domain) + hardswish ----
__global__ __launch_bounds__(256) void combine_kernel(const float* __restrict__ pm,
                                                      const float* __restrict__ pl,
                                                      const float* __restrict__ pacc,
                                                      float* __restrict__ attn_o)
{
    int i = blockIdx.x * 256 + threadIdx.x;
    int r = i >> 5, e = i & 31;
    float m0 = pm[r], m1 = pm[NROWS + r], m2 = pm[2 * NROWS + r], m3 = pm[3 * NROWS + r];
    float M = fmaxf(fmaxf(m0, m1), fmaxf(m2, m3));
    float w0 = fexp2(m0 - M), w1 = fexp2(m1 - M), w2 = fexp2(m2 - M), w3 = fexp2(m3 - M);
    float L = pl[r] * w0 + pl[NROWS + r] * w1 + pl[2 * NROWS + r] * w2 + pl[3 * NROWS + r] * w3;
    float v = pacc[(size_t)r * 32 + e] * w0 + pacc[(size_t)(NROWS + r) * 32 + e] * w1
            + pacc[(size_t)(2 * NROWS + r) * 32 + e] * w2 + pacc[(size_t)(3 * NROWS + r) * 32 + e] * w3;
    v /= L;
    float hs = v * fminf(fmaxf(v + 3.f, 0.f), 6.f) * (1.f / 6.f);
    int q = r % N_Q;
    int bh = r / N_Q;
    int hh = bh & 7, b = bh >> 3;
    attn_o[(size_t)(b * N_Q + q) * 256 + hh * 32 + e] = hs;
}

extern "C" void kernel_launch(void* const* d_in, const int* in_sizes, int n_in,
                              void* d_out, int out_size, void* d_ws, size_t ws_size,
                              hipStream_t stream) {
    (void)n_in; (void)out_size; (void)ws_size;
    const float* x      = (const float*)d_in[0];
    const float* kv_w   = (const float*)d_in[1];
    const float* kv_g   = (const float*)d_in[2];
    const float* kv_b   = (const float*)d_in[3];
    const float* q_w    = (const float*)d_in[4];
    const float* q_g    = (const float*)d_in[5];
    const float* q_b    = (const float*)d_in[6];
    const float* proj_w = (const float*)d_in[7];
    const float* proj_g = (const float*)d_in[8];
    const float* proj_b = (const float*)d_in[9];
    const float* bias_table = (const float*)d_in[10];
    const int*   bias_idxs  = (const int*)d_in[11];
    const int    n_off = in_sizes[10] / 8;
    float* out = (float*)d_out;

    float* ws = (float*)d_ws;
    float* kv_y     = ws;                          // 10584*384
    float* q_y      = kv_y + 10584 * 384;          // 2688*128
    float* attn_o   = q_y + 2688 * 128;            // 2688*256
    float* pacc     = attn_o + 2688 * 256;         // 4*21504*32
    float* proj_y   = pacc;                        // overlays pacc (dead after combine)
    float* pm       = pacc + 4 * NROWS * 32;
    float* pl       = pm + 4 * NROWS;
    float* sums_kv  = pl + 4 * NROWS;              // 768
    float* sums_q   = sums_kv + 768;               // 256
    float* sums_p   = sums_q + 256;                // 1024
    float* kv_sc    = sums_p + 1024;               // 384
    float* kv_sh    = kv_sc + 384;                 // 384
    float* q_sc     = kv_sh + 384;                 // 128
    float* q_sh     = q_sc + 128;                  // 128
    float* bt_r     = q_sh + 128;                  // 8*5292 f32

    zero_f<<<8, 256, 0, stream>>>(sums_kv, 2048);

    // GEMMs (MFMA hi/lo) with fused stats
    gemm_mfma<<<dim3(6, 166), 256, 0, stream>>>(x, kv_w, kv_y, sums_kv, 10584, 384, 0);
    gemm_mfma<<<dim3(2, 42), 256, 0, stream>>>(x, q_w, q_y, sums_q, 2688, 128, 1);
    bias_remap<<<166, 256, 0, stream>>>(bias_table, bias_idxs, bt_r, n_off);
    bn_coeffs<<<2, 256, 0, stream>>>(sums_kv, sums_q, kv_g, kv_b, q_g, q_b,
                                     kv_sc, kv_sh, q_sc, q_sh);

    // MFMA flash attention -> partials -> combine(+hardswish)
    attn_mfma<<<dim3(21, 8, 8), 256, 0, stream>>>(kv_y, q_y, kv_sc, kv_sh, q_sc, q_sh,
                                                  bt_r, pm, pl, pacc);
    combine_kernel<<<2688, 256, 0, stream>>>(pm, pl, pacc, attn_o);

    // proj
    gemm_mfma<<<dim3(8, 42), 256, 0, stream>>>(attn_o, proj_w, proj_y, sums_p, 2688, 512, 0);
    norm_apply<<<dim3(8, 84), 256, 0, stream>>>(proj_y, sums_p, proj_g, proj_b, out,
                                                2688, 512, 1.f / 2688.f);
}

// Round 5
// 261.561 us; speedup vs baseline: 1.2306x; 1.2306x over previous
//
#include <hip/hip_runtime.h>
#include <hip/hip_bf16.h>
#include <math.h>

#define N_K 5292
#define N_Q 1344
#define NH_KD 128
#define OUT_DIM 512
#define NROWS 21504   // 2*8*1344 (b,h,q) rows of partials
#define LOG2E 1.4426950408889634f

typedef float f32x4 __attribute__((ext_vector_type(4)));
typedef short short8 __attribute__((ext_vector_type(8)));

__device__ __forceinline__ float fexp2(float x) {
#if __has_builtin(__builtin_amdgcn_exp2f)
    return __builtin_amdgcn_exp2f(x);
#else
    return exp2f(x);
#endif
}

// packed f32x2 -> bf16x2 (v_cvt_pk_bf16_f32); a in low 16 bits
__device__ __forceinline__ unsigned pk_bf16(float a, float b) {
    union { __hip_bfloat162 h; unsigned u; } c;
    c.h = __float22bfloat162_rn(make_float2(a, b));
    return c.u;
}

// fp32x4 -> bf16 hi + bf16 lo (residual), packed
__device__ __forceinline__ void hilo_pk(float4 v, uint2& hi, uint2& lo) {
    unsigned h0 = pk_bf16(v.x, v.y);
    unsigned h1 = pk_bf16(v.z, v.w);
    float hx = __uint_as_float(h0 << 16);
    float hy = __uint_as_float(h0 & 0xffff0000u);
    float hz = __uint_as_float(h1 << 16);
    float hw = __uint_as_float(h1 & 0xffff0000u);
    hi = make_uint2(h0, h1);
    lo = make_uint2(pk_bf16(v.x - hx, v.y - hy), pk_bf16(v.z - hz, v.w - hw));
}

// ---------------- zero scratch ----------------
__global__ void zero_f(float* __restrict__ p, int n) {
    int i = blockIdx.x * 256 + threadIdx.x;
    if (i < n) p[i] = 0.f;
}

// ---- pack fp32 -> bf16 hi/lo planes ----
__global__ void pack_hilo(const float* __restrict__ src, unsigned short* __restrict__ hi,
                          unsigned short* __restrict__ lo, int n4) {
    int i = blockIdx.x * 256 + threadIdx.x;
    if (i < n4) {
        float4 v = ((const float4*)src)[i];
        uint2 h, l;
        hilo_pk(v, h, l);
        ((uint2*)hi)[i] = h;
        ((uint2*)lo)[i] = l;
    }
}

// pack the three weight matrices into one concatenated hi/lo plane pair
__global__ void pack_w(const float* __restrict__ a, int na4,
                       const float* __restrict__ b, int nb4,
                       const float* __restrict__ c, int nc4,
                       unsigned short* __restrict__ hi, unsigned short* __restrict__ lo) {
    int i = blockIdx.x * 256 + threadIdx.x;
    int j = i;
    const float* s;
    if (j < na4) s = a;
    else if ((j -= na4) < nb4) s = b;
    else if ((j -= nb4) < nc4) s = c;
    else return;
    float4 v = ((const float4*)s)[j];
    uint2 h, l;
    hilo_pk(v, h, l);
    ((uint2*)hi)[i] = h;
    ((uint2*)lo)[i] = l;
}

// ---- MFMA GEMM on packed hi/lo planes. Y = A(row(m),:) . W(n,:)^T, K=256.
// Fused column sum/sumsq. 1D swizzled grid: xcd = id&7, m-tile = xcd + 8*(id8/nblk),
// so all n-blocks of an m-stripe land on one XCD (X fetched once into its L2).
__global__ __launch_bounds__(256) void gemm_p(
    const unsigned short* __restrict__ Ah, const unsigned short* __restrict__ Al,
    const unsigned short* __restrict__ Wh, const unsigned short* __restrict__ Wl,
    float* __restrict__ Y, float* __restrict__ sums,
    int M, int Ncols, int mtiles, int nblk, int mode)
{
    const int id = blockIdx.x;
    const int xcd = id & 7;
    const int id8 = id >> 3;
    const int my = xcd + (id8 / nblk) * 8;
    const int ny = id8 % nblk;
    if (my >= mtiles) return;

    __shared__ unsigned short As_h[64][40], As_l[64][40], Bs_h[64][40], Bs_l[64][40];
    const int t = threadIdx.x;
    const int w = t >> 6, lane = t & 63, g = lane >> 4, ln = lane & 15;
    const int m0 = my * 64, n0 = ny * 64;
    const int srow = t >> 2;         // staged row 0..63
    const int sc8 = (t & 3) * 8;     // 8 shorts per thread per plane

    int mrow = m0 + srow;
    long asrc = -1;
    if (mrow < M) {
        if (mode == 1) {
            int bb = mrow / N_Q;
            int i = mrow - bb * N_Q;
            asrc = (long)(bb * N_K + (i / 42) * 168 + (i % 42) * 2);
        } else asrc = mrow;
    }
    const int nrow = n0 + srow;      // Ncols multiple of 64

    f32x4 acc[4];
    #pragma unroll
    for (int nt = 0; nt < 4; ++nt) acc[nt] = (f32x4){0.f, 0.f, 0.f, 0.f};

    for (int k0 = 0; k0 < 256; k0 += 32) {
        uint4 a_h = make_uint4(0, 0, 0, 0), a_l = a_h;
        if (asrc >= 0) {
            a_h = *(const uint4*)(Ah + asrc * 256 + k0 + sc8);
            a_l = *(const uint4*)(Al + asrc * 256 + k0 + sc8);
        }
        uint4 b_h = *(const uint4*)(Wh + (size_t)nrow * 256 + k0 + sc8);
        uint4 b_l = *(const uint4*)(Wl + (size_t)nrow * 256 + k0 + sc8);

        __syncthreads();
        *(uint4*)&As_h[srow][sc8] = a_h;
        *(uint4*)&As_l[srow][sc8] = a_l;
        *(uint4*)&Bs_h[srow][sc8] = b_h;
        *(uint4*)&Bs_l[srow][sc8] = b_l;
        __syncthreads();

        short8 ah = *(const short8*)&As_h[w * 16 + ln][g * 8];
        short8 al = *(const short8*)&As_l[w * 16 + ln][g * 8];
        #pragma unroll
        for (int nt = 0; nt < 4; ++nt) {
            short8 bh = *(const short8*)&Bs_h[nt * 16 + ln][g * 8];
            short8 bl = *(const short8*)&Bs_l[nt * 16 + ln][g * 8];
            acc[nt] = __builtin_amdgcn_mfma_f32_16x16x32_bf16(al, bh, acc[nt], 0, 0, 0);
            acc[nt] = __builtin_amdgcn_mfma_f32_16x16x32_bf16(ah, bl, acc[nt], 0, 0, 0);
            acc[nt] = __builtin_amdgcn_mfma_f32_16x16x32_bf16(ah, bh, acc[nt], 0, 0, 0);
        }
    }

    #pragma unroll
    for (int nt = 0; nt < 4; ++nt) {
        #pragma unroll
        for (int reg = 0; reg < 4; ++reg) {
            int mr = m0 + w * 16 + g * 4 + reg;
            if (mr < M) Y[(size_t)mr * Ncols + n0 + nt * 16 + ln] = acc[nt][reg];
        }
    }

    // fused column stats (OOB rows contribute zeros)
    float s4[4], q4[4];
    #pragma unroll
    for (int nt = 0; nt < 4; ++nt) {
        float s = acc[nt][0] + acc[nt][1] + acc[nt][2] + acc[nt][3];
        float q = fmaf(acc[nt][0], acc[nt][0], fmaf(acc[nt][1], acc[nt][1],
                  fmaf(acc[nt][2], acc[nt][2], acc[nt][3] * acc[nt][3])));
        s += __shfl_xor(s, 16); s += __shfl_xor(s, 32);
        q += __shfl_xor(q, 16); q += __shfl_xor(q, 32);
        s4[nt] = s; q4[nt] = q;
    }
    __syncthreads();
    float* st_s = (float*)&As_h[0][0];
    float* st_q = st_s + 256;
    if (g == 0) {
        #pragma unroll
        for (int nt = 0; nt < 4; ++nt) {
            st_s[(w * 4 + nt) * 16 + ln] = s4[nt];
            st_q[(w * 4 + nt) * 16 + ln] = q4[nt];
        }
    }
    __syncthreads();
    if (t < 64) {
        int nt = t >> 4, c = t & 15;
        float a = 0.f, b2 = 0.f;
        #pragma unroll
        for (int ww = 0; ww < 4; ++ww) {
            a  += st_s[(ww * 4 + nt) * 16 + c];
            b2 += st_q[(ww * 4 + nt) * 16 + c];
        }
        atomicAdd(&sums[n0 + nt * 16 + c], a);
        atomicAdd(&sums[Ncols + n0 + nt * 16 + c], b2);
    }
}

// ---- BN coeffs for kv (384) and q (128, scale*log2e folded) ----
__global__ void bn_coeffs(const float* __restrict__ sums_kv, const float* __restrict__ sums_q,
                          const float* __restrict__ kv_g, const float* __restrict__ kv_b,
                          const float* __restrict__ q_g, const float* __restrict__ q_b,
                          float* __restrict__ kv_sc, float* __restrict__ kv_sh,
                          float* __restrict__ q_sc, float* __restrict__ q_sh)
{
    int c = blockIdx.x * 256 + threadIdx.x;
    if (c < 384) {
        float inv = 1.f / 10584.f;
        float mu  = sums_kv[c] * inv;
        float var = fmaf(-mu, mu, sums_kv[384 + c] * inv);
        float s   = kv_g[c] * rsqrtf(var + 1e-5f);
        kv_sc[c] = s;
        kv_sh[c] = fmaf(-mu, s, kv_b[c]);
    } else if (c < 512) {
        int cc = c - 384;
        float inv = 1.f / 2688.f;
        float post = 0.25f * LOG2E;
        float mu  = sums_q[cc] * inv;
        float var = fmaf(-mu, mu, sums_q[128 + cc] * inv);
        float s   = q_g[cc] * rsqrtf(var + 1e-5f) * post;
        q_sc[cc] = s;
        q_sh[cc] = fmaf(-mu, s, q_b[cc] * post);
    }
}

// ---- kv_pack: BN-normalize kv_y and repack per head as bf16:
// Kp[b][h][key][16], Vp[b][h][key][32] ----
__global__ __launch_bounds__(256) void kv_pack(const float* __restrict__ kv_y,
                                               const float* __restrict__ kv_sc,
                                               const float* __restrict__ kv_sh,
                                               unsigned short* __restrict__ Kp,
                                               unsigned short* __restrict__ Vp)
{
    int i = blockIdx.x * 256 + threadIdx.x;          // (b,h,key,c4), c4 fastest
    if (i >= 2 * 8 * N_K * 12) return;
    int c4 = i % 12;
    int key = (i / 12) % N_K;
    int h = (i / (12 * N_K)) & 7;
    int b = i / (12 * N_K * 8);
    int ch = h * 48 + c4 * 4;
    float4 v = *(const float4*)(kv_y + (size_t)(b * N_K + key) * 384 + ch);
    float4 sc = *(const float4*)(kv_sc + ch);
    float4 sh = *(const float4*)(kv_sh + ch);
    v.x = fmaf(v.x, sc.x, sh.x); v.y = fmaf(v.y, sc.y, sh.y);
    v.z = fmaf(v.z, sc.z, sh.z); v.w = fmaf(v.w, sc.w, sh.w);
    uint2 u = make_uint2(pk_bf16(v.x, v.y), pk_bf16(v.z, v.w));
    size_t slot = (size_t)(b * 8 + h) * N_K + key;
    if (c4 < 4) *(uint2*)((unsigned*)Kp + slot * 8 + c4 * 2) = u;
    else        *(uint2*)((unsigned*)Vp + slot * 16 + (c4 - 4) * 2) = u;
}

// ---- bias remap: bt_r[h][dr*84+dc] = bias_table[h][rank] * log2e ----
__global__ void bias_remap(const float* __restrict__ bias_table, const int* __restrict__ bias_idxs,
                           float* __restrict__ bt_r, int n_off)
{
    int i = blockIdx.x * 256 + threadIdx.x;
    if (i < 8 * N_K) {
        int h = i / N_K, j = i - h * N_K;
        bt_r[i] = bias_table[h * n_off + bias_idxs[j]] * LOG2E;
    }
}

// ---- MFMA flash attention, 4-way key split, packed bf16 KV, XCD-pinned grid ----
// 1D grid 1344: h = id&7 (pins head -> XCD), z = (id>>3)&7 (b*4+ks), qt = id>>6.
__global__ __launch_bounds__(256, 6) void attn_mfma(
    const unsigned short* __restrict__ Kp, const unsigned short* __restrict__ Vp,
    const float* __restrict__ q_y,
    const float* __restrict__ q_sc, const float* __restrict__ q_sh,
    const float* __restrict__ bt_r,
    float* __restrict__ pm, float* __restrict__ pl, float* __restrict__ pacc)
{
    const int id = blockIdx.x;
    const int h = id & 7;
    const int z = (id >> 3) & 7;
    const int qt = id >> 6;
    const int b = z >> 2, ks = z & 3;
    const int t = threadIdx.x;
    const int w = t >> 6, lane = t & 63, g = lane >> 4, ln = lane & 15;

    __shared__ float bt_s[21 * 84];            // 7056 B window
    __shared__ unsigned short K_s[64][24];     // 3072 B
    __shared__ unsigned short Vt_s[32][72];    // 4608 B
    __shared__ unsigned short P_s[4][16][72];  // 9216 B

    const int q0 = qt * 64;
    const int kstart = ks * 1344;
    const int kend = (kstart + 1344 < N_K) ? kstart + 1344 : N_K;

    // bias window rows
    const int kr0 = ks * 16;
    const int kr1 = (kend - 1) / 84;
    const int rq2min = (q0 / 42) * 2;
    const int rq2max = ((q0 + 63) / 42) * 2;
    int dr_lo = 0;
    if (rq2min > kr1) dr_lo = rq2min - kr1;
    else if (kr0 > rq2max) dr_lo = kr0 - rq2max;
    int a1 = rq2max - kr0, a2 = kr1 - rq2min;
    int dr_hi = a1 > a2 ? a1 : a2;
    {
        int nb = (dr_hi - dr_lo + 1) * 84;
        const float* src = bt_r + h * N_K + dr_lo * 84;
        for (int j = t; j < nb; j += 256) bt_s[j] = src[j];
    }

    // Q A-fragment (BN+scale applied); k=d<16 -> lane groups 2,3 zero
    short8 qfrag = (short8)0;
    if (lane < 32) {
        const float* qp = q_y + (size_t)(b * N_Q + q0 + w * 16 + ln) * NH_KD + h * 16 + g * 8;
        float4 q0v = *(const float4*)qp;
        float4 q1v = *(const float4*)(qp + 4);
        const float* scp = q_sc + h * 16 + g * 8;
        const float* shp = q_sh + h * 16 + g * 8;
        q0v.x = fmaf(q0v.x, scp[0], shp[0]); q0v.y = fmaf(q0v.y, scp[1], shp[1]);
        q0v.z = fmaf(q0v.z, scp[2], shp[2]); q0v.w = fmaf(q0v.w, scp[3], shp[3]);
        q1v.x = fmaf(q1v.x, scp[4], shp[4]); q1v.y = fmaf(q1v.y, scp[5], shp[5]);
        q1v.z = fmaf(q1v.z, scp[6], shp[6]); q1v.w = fmaf(q1v.w, scp[7], shp[7]);
        union { short8 s; unsigned u[4]; } qf;
        qf.u[0] = pk_bf16(q0v.x, q0v.y); qf.u[1] = pk_bf16(q0v.z, q0v.w);
        qf.u[2] = pk_bf16(q1v.x, q1v.y); qf.u[3] = pk_bf16(q1v.z, q1v.w);
        qfrag = qf.s;
    }

    int rq2[4], cq2[4];
    #pragma unroll
    for (int reg = 0; reg < 4; ++reg) {
        int qg = q0 + w * 16 + g * 4 + reg;
        rq2[reg] = (qg / 42) * 2;
        cq2[reg] = (qg % 42) * 2;
    }
    int kr[4], kc[4];
    #pragma unroll
    for (int st = 0; st < 4; ++st) {
        int kg = kstart + st * 16 + ln;
        kr[st] = kg / 84;
        kc[st] = kg - kr[st] * 84;
    }

    const unsigned* kp_base = (const unsigned*)Kp + (size_t)(b * 8 + h) * N_K * 8;
    const unsigned* vp_base = (const unsigned*)Vp + (size_t)(b * 8 + h) * N_K * 16;
    const int skey = t >> 2, schunk = t & 3;

    float m[4], l[4];
    #pragma unroll
    for (int r = 0; r < 4; ++r) { m[r] = -1e30f; l[r] = 0.f; }
    f32x4 acc0 = {0.f, 0.f, 0.f, 0.f}, acc1 = {0.f, 0.f, 0.f, 0.f};
    const f32x4 zero4 = {0.f, 0.f, 0.f, 0.f};

    for (int k0 = kstart; k0 < kend; k0 += 64) {
        __syncthreads();
        { // stage K: straight uint2 copy, 2 KB
            int kg = k0 + skey;
            uint2 u = make_uint2(0, 0);
            if (kg < N_K) u = *(const uint2*)(kp_base + (size_t)kg * 8 + schunk * 2);
            *(uint2*)&K_s[skey][schunk * 4] = u;
        }
        { // stage V: uint4 load + 8-way b16 transpose scatter, 4 KB
            int kg = k0 + skey;
            uint4 u = make_uint4(0, 0, 0, 0);
            if (kg < N_K) u = *(const uint4*)(vp_base + (size_t)kg * 16 + schunk * 4);
            int v0 = schunk * 8;
            Vt_s[v0 + 0][skey] = (unsigned short)u.x;
            Vt_s[v0 + 1][skey] = (unsigned short)(u.x >> 16);
            Vt_s[v0 + 2][skey] = (unsigned short)u.y;
            Vt_s[v0 + 3][skey] = (unsigned short)(u.y >> 16);
            Vt_s[v0 + 4][skey] = (unsigned short)u.z;
            Vt_s[v0 + 5][skey] = (unsigned short)(u.z >> 16);
            Vt_s[v0 + 6][skey] = (unsigned short)u.w;
            Vt_s[v0 + 7][skey] = (unsigned short)(u.w >> 16);
        }
        __syncthreads();

        // QK^T
        f32x4 sf[4];
        #pragma unroll
        for (int st = 0; st < 4; ++st) {
            short8 bf = (short8)0;
            if (lane < 32) bf = *(const short8*)&K_s[st * 16 + ln][g * 8];
            sf[st] = __builtin_amdgcn_mfma_f32_16x16x32_bf16(qfrag, bf, zero4, 0, 0, 0);
        }

        // bias + mask + row max (log2 domain)
        float scv[4][4];
        float rmax[4] = {-1e30f, -1e30f, -1e30f, -1e30f};
        #pragma unroll
        for (int st = 0; st < 4; ++st) {
            bool valid = (k0 + st * 16 + ln) < N_K;
            #pragma unroll
            for (int reg = 0; reg < 4; ++reg) {
                int dr = rq2[reg] - kr[st]; dr = dr < 0 ? -dr : dr;
                int dc = cq2[reg] - kc[st]; dc = dc < 0 ? -dc : dc;
                float v = sf[st][reg] + bt_s[(dr - dr_lo) * 84 + dc];
                v = valid ? v : -1e30f;
                scv[st][reg] = v;
                rmax[reg] = fmaxf(rmax[reg], v);
            }
        }
        #pragma unroll
        for (int reg = 0; reg < 4; ++reg) {
            float r = rmax[reg];
            r = fmaxf(r, __shfl_xor(r, 1, 16));
            r = fmaxf(r, __shfl_xor(r, 2, 16));
            r = fmaxf(r, __shfl_xor(r, 4, 16));
            r = fmaxf(r, __shfl_xor(r, 8, 16));
            rmax[reg] = r;
        }

        // online update + P -> LDS
        #pragma unroll
        for (int reg = 0; reg < 4; ++reg) {
            float mn = fmaxf(m[reg], rmax[reg]);
            float alpha = fexp2(m[reg] - mn);
            m[reg] = mn;
            l[reg] *= alpha;
            acc0[reg] *= alpha;
            acc1[reg] *= alpha;
            float p0 = fexp2(scv[0][reg] - mn);
            float p1 = fexp2(scv[1][reg] - mn);
            float p2 = fexp2(scv[2][reg] - mn);
            float p3 = fexp2(scv[3][reg] - mn);
            l[reg] += (p0 + p1) + (p2 + p3);
            unsigned u01 = pk_bf16(p0, p1), u23 = pk_bf16(p2, p3);
            P_s[w][g * 4 + reg][ln]      = (unsigned short)u01;
            P_s[w][g * 4 + reg][16 + ln] = (unsigned short)(u01 >> 16);
            P_s[w][g * 4 + reg][32 + ln] = (unsigned short)u23;
            P_s[w][g * 4 + reg][48 + ln] = (unsigned short)(u23 >> 16);
        }

        // PV
        #pragma unroll
        for (int kt = 0; kt < 2; ++kt) {
            short8 af = *(const short8*)&P_s[w][ln][g * 8 + kt * 32];
            short8 b0 = *(const short8*)&Vt_s[ln][g * 8 + kt * 32];
            short8 b1 = *(const short8*)&Vt_s[ln + 16][g * 8 + kt * 32];
            acc0 = __builtin_amdgcn_mfma_f32_16x16x32_bf16(af, b0, acc0, 0, 0, 0);
            acc1 = __builtin_amdgcn_mfma_f32_16x16x32_bf16(af, b1, acc1, 0, 0, 0);
        }

        #pragma unroll
        for (int st = 0; st < 4; ++st) {
            kc[st] += 64;
            if (kc[st] >= 84) { kc[st] -= 84; kr[st] += 1; }
        }
    }

    #pragma unroll
    for (int reg = 0; reg < 4; ++reg) {
        float s = l[reg];
        s += __shfl_xor(s, 1, 16);
        s += __shfl_xor(s, 2, 16);
        s += __shfl_xor(s, 4, 16);
        s += __shfl_xor(s, 8, 16);
        l[reg] = s;
    }

    const int rbase = (b * 8 + h) * N_Q + q0 + w * 16;
    #pragma unroll
    for (int reg = 0; reg < 4; ++reg) {
        int prow = ks * NROWS + rbase + g * 4 + reg;
        pacc[(size_t)prow * 32 + ln]      = acc0[reg];
        pacc[(size_t)prow * 32 + 16 + ln] = acc1[reg];
        if (ln == 0) { pm[prow] = m[reg]; pl[prow] = l[reg]; }
    }
}

// ---- combine 4 key-split partials + hardswish -> bf16 hi/lo planes ----
__global__ __launch_bounds__(256) void combine_kernel(const float* __restrict__ pm,
                                                      const float* __restrict__ pl,
                                                      const float* __restrict__ pacc,
                                                      unsigned short* __restrict__ oh,
                                                      unsigned short* __restrict__ ol)
{
    int i = blockIdx.x * 256 + threadIdx.x;
    int r = i >> 5, e = i & 31;
    float m0 = pm[r], m1 = pm[NROWS + r], m2 = pm[2 * NROWS + r], m3 = pm[3 * NROWS + r];
    float M = fmaxf(fmaxf(m0, m1), fmaxf(m2, m3));
    float w0 = fexp2(m0 - M), w1 = fexp2(m1 - M), w2 = fexp2(m2 - M), w3 = fexp2(m3 - M);
    float L = pl[r] * w0 + pl[NROWS + r] * w1 + pl[2 * NROWS + r] * w2 + pl[3 * NROWS + r] * w3;
    float v = pacc[(size_t)r * 32 + e] * w0 + pacc[(size_t)(NROWS + r) * 32 + e] * w1
            + pacc[(size_t)(2 * NROWS + r) * 32 + e] * w2 + pacc[(size_t)(3 * NROWS + r) * 32 + e] * w3;
    v /= L;
    float hs = v * fminf(fmaxf(v + 3.f, 0.f), 6.f) * (1.f / 6.f);
    unsigned hu = pk_bf16(hs, 0.f) & 0xffffu;
    float hf = __uint_as_float(hu << 16);
    unsigned lu = pk_bf16(hs - hf, 0.f) & 0xffffu;
    int q = r % N_Q;
    int bh = r / N_Q;
    int hh = bh & 7, b = bh >> 3;
    size_t idx = (size_t)(b * N_Q + q) * 256 + hh * 32 + e;
    oh[idx] = (unsigned short)hu;
    ol[idx] = (unsigned short)lu;
}

// ---- final BN apply ----
__global__ __launch_bounds__(256) void norm_apply(
    const float* __restrict__ Y, const float* __restrict__ sums,
    const float* __restrict__ g, const float* __restrict__ bb,
    float* __restrict__ out, int rows, int cols, float inv_rows)
{
    __shared__ float sc_s[64], sh_s[64];
    const int t = threadIdx.x;
    const int c0 = blockIdx.x * 64;
    if (t < 64) {
        int c = c0 + t;
        float mu  = sums[c] * inv_rows;
        float var = fmaf(-mu, mu, sums[cols + c] * inv_rows);
        float s   = g[c] * rsqrtf(var + 1e-5f);
        sc_s[t] = s;
        sh_s[t] = fmaf(-mu, s, bb[c]);
    }
    __syncthreads();
    const int c4 = (t & 15) * 4;
    float4 scv = *(const float4*)&sc_s[c4];
    float4 shv = *(const float4*)&sh_s[c4];
    for (int r = blockIdx.y * 16 + (t >> 4); r < rows; r += gridDim.y * 16) {
        size_t off = (size_t)r * cols + c0 + c4;
        float4 v = *(const float4*)(Y + off);
        v.x = fmaf(v.x, scv.x, shv.x);
        v.y = fmaf(v.y, scv.y, shv.y);
        v.z = fmaf(v.z, scv.z, shv.z);
        v.w = fmaf(v.w, scv.w, shv.w);
        *(float4*)(out + off) = v;
    }
}

extern "C" void kernel_launch(void* const* d_in, const int* in_sizes, int n_in,
                              void* d_out, int out_size, void* d_ws, size_t ws_size,
                              hipStream_t stream) {
    (void)n_in; (void)out_size; (void)ws_size;
    const float* x      = (const float*)d_in[0];
    const float* kv_w   = (const float*)d_in[1];
    const float* kv_g   = (const float*)d_in[2];
    const float* kv_b   = (const float*)d_in[3];
    const float* q_w    = (const float*)d_in[4];
    const float* q_g    = (const float*)d_in[5];
    const float* q_b    = (const float*)d_in[6];
    const float* proj_w = (const float*)d_in[7];
    const float* proj_g = (const float*)d_in[8];
    const float* proj_b = (const float*)d_in[9];
    const float* bias_table = (const float*)d_in[10];
    const int*   bias_idxs  = (const int*)d_in[11];
    const int    n_off = in_sizes[10] / 8;
    float* out = (float*)d_out;

    float* ws = (float*)d_ws;
    float* kv_y = ws;                                   // 4,064,256
    float* q_y  = kv_y + 10584 * 384;                   // 344,064
    float* regA = q_y + 2688 * 128;                     // 2,752,512 (X planes -> pacc -> proj_y)
    unsigned short* Xh = (unsigned short*)regA;         // 10584*256 shorts
    unsigned short* Xl = Xh + 10584 * 256;
    float* pacc   = regA;
    float* proj_y = regA;
    float* pm = regA + 4 * NROWS * 32;                  // 86,016
    float* pl = pm + 4 * NROWS;                         // 86,016
    unsigned short* Wh = (unsigned short*)(pl + 4 * NROWS);   // 1024*256 shorts
    unsigned short* Wl = Wh + 1024 * 256;
    unsigned short* attn_oh = Wl + 1024 * 256;          // 2688*256 shorts
    unsigned short* attn_ol = attn_oh + 2688 * 256;
    unsigned short* Kp = attn_ol + 2688 * 256;          // 2*8*5292*16 shorts
    unsigned short* Vp = Kp + 2 * 8 * N_K * 16;         // 2*8*5292*32 shorts
    float* sums_kv = (float*)(Vp + 2 * 8 * N_K * 32);   // 768
    float* sums_q  = sums_kv + 768;                     // 256
    float* sums_p  = sums_q + 256;                      // 1024
    float* kv_sc   = sums_p + 1024;
    float* kv_sh   = kv_sc + 384;
    float* q_sc    = kv_sh + 384;
    float* q_sh    = q_sc + 128;
    float* bt_r    = q_sh + 128;                        // 8*5292

    zero_f<<<8, 256, 0, stream>>>(sums_kv, 2048);

    // pack inputs to bf16 hi/lo planes
    pack_hilo<<<2646, 256, 0, stream>>>(x, Xh, Xl, 10584 * 64);
    pack_w<<<256, 256, 0, stream>>>(kv_w, 384 * 64, q_w, 128 * 64, proj_w, 512 * 64, Wh, Wl);

    // GEMMs (packed, swizzled grids): kv mtiles=166 nblk=6; q mtiles=42 nblk=2
    gemm_p<<<8 * 21 * 6, 256, 0, stream>>>(Xh, Xl, Wh, Wl, kv_y, sums_kv,
                                           10584, 384, 166, 6, 0);
    gemm_p<<<8 * 6 * 2, 256, 0, stream>>>(Xh, Xl, Wh + 384 * 256, Wl + 384 * 256, q_y, sums_q,
                                          2688, 128, 42, 2, 1);
    bias_remap<<<166, 256, 0, stream>>>(bias_table, bias_idxs, bt_r, n_off);
    bn_coeffs<<<2, 256, 0, stream>>>(sums_kv, sums_q, kv_g, kv_b, q_g, q_b,
                                     kv_sc, kv_sh, q_sc, q_sh);

    // BN + per-head bf16 repack of K/V
    kv_pack<<<3969, 256, 0, stream>>>(kv_y, kv_sc, kv_sh, Kp, Vp);

    // flash attention (XCD-pinned) -> partials -> combine(+hardswish, hi/lo out)
    attn_mfma<<<1344, 256, 0, stream>>>(Kp, Vp, q_y, q_sc, q_sh, bt_r, pm, pl, pacc);
    combine_kernel<<<2688, 256, 0, stream>>>(pm, pl, pacc, attn_oh, attn_ol);

    // proj (packed A from combine): mtiles=42 nblk=8
    gemm_p<<<8 * 6 * 8, 256, 0, stream>>>(attn_oh, attn_ol, Wh + 512 * 256, Wl + 512 * 256,
                                          proj_y, sums_p, 2688, 512, 42, 8, 0);
    norm_apply<<<dim3(8, 84), 256, 0, stream>>>(proj_y, sums_p, proj_g, proj_b, out,
                                                2688, 512, 1.f / 2688.f);
}

// Round 6
// 222.114 us; speedup vs baseline: 1.4492x; 1.1776x over previous
//
#include <hip/hip_runtime.h>
#include <hip/hip_bf16.h>
#include <math.h>

#define N_K 5292
#define N_Q 1344
#define NH_KD 128
#define NROWS 21504   // 2*8*1344 (b,h,q) rows of partials
#define LOG2E 1.4426950408889634f
#define MSTAT 16.0f   // static softmax shift (log2 domain), folded into bias

typedef float f32x4 __attribute__((ext_vector_type(4)));
typedef short short8 __attribute__((ext_vector_type(8)));

__device__ __forceinline__ float fexp2(float x) {
#if __has_builtin(__builtin_amdgcn_exp2f)
    return __builtin_amdgcn_exp2f(x);
#else
    return exp2f(x);
#endif
}

// packed f32x2 -> bf16x2 (v_cvt_pk_bf16_f32); a in low 16 bits
__device__ __forceinline__ unsigned pk_bf16(float a, float b) {
    union { __hip_bfloat162 h; unsigned u; } c;
    c.h = __float22bfloat162_rn(make_float2(a, b));
    return c.u;
}

// fp32x4 -> bf16 hi + bf16 lo (residual), packed
__device__ __forceinline__ void hilo_pk(float4 v, uint2& hi, uint2& lo) {
    unsigned h0 = pk_bf16(v.x, v.y);
    unsigned h1 = pk_bf16(v.z, v.w);
    float hx = __uint_as_float(h0 << 16);
    float hy = __uint_as_float(h0 & 0xffff0000u);
    float hz = __uint_as_float(h1 << 16);
    float hw = __uint_as_float(h1 & 0xffff0000u);
    hi = make_uint2(h0, h1);
    lo = make_uint2(pk_bf16(v.x - hx, v.y - hy), pk_bf16(v.z - hz, v.w - hw));
}

// ---- fused prep: zero stats | pack X hi/lo | pack W hi/lo | bias remap ----
__global__ __launch_bounds__(256) void prep_kernel(
    const float* __restrict__ x, const float* __restrict__ kv_w,
    const float* __restrict__ q_w, const float* __restrict__ proj_w,
    const float* __restrict__ bias_table, const int* __restrict__ bias_idxs, int n_off,
    float* __restrict__ sums, unsigned short* __restrict__ Xh, unsigned short* __restrict__ Xl,
    unsigned short* __restrict__ Wh, unsigned short* __restrict__ Wl,
    float* __restrict__ bt_r)
{
    int bid = blockIdx.x;
    const int t = threadIdx.x;
    if (bid < 8) {                                  // zero 2048 stats floats
        int i = bid * 256 + t;
        if (i < 2048) sums[i] = 0.f;
        return;
    }
    bid -= 8;
    if (bid < 2646) {                               // pack X
        int i = bid * 256 + t;                      // exactly 677376
        float4 v = ((const float4*)x)[i];
        uint2 h, l;
        hilo_pk(v, h, l);
        ((uint2*)Xh)[i] = h;
        ((uint2*)Xl)[i] = l;
        return;
    }
    bid -= 2646;
    if (bid < 256) {                                // pack W (kv|q|proj concat)
        int i = bid * 256 + t;                      // exactly 65536
        int j = i;
        const float* s;
        if (j < 384 * 64) s = kv_w;
        else if ((j -= 384 * 64) < 128 * 64) s = q_w;
        else { j -= 128 * 64; s = proj_w; }
        float4 v = ((const float4*)s)[j];
        uint2 h, l;
        hilo_pk(v, h, l);
        ((uint2*)Wh)[i] = h;
        ((uint2*)Wl)[i] = l;
        return;
    }
    bid -= 256;
    {                                               // bias remap (log2e, -MSTAT folded)
        int i = bid * 256 + t;
        if (i < 8 * N_K) {
            int h = i / N_K, j = i - h * N_K;
            bt_r[i] = fmaf(bias_table[h * n_off + bias_idxs[j]], LOG2E, -MSTAT);
        }
    }
}

// ---- MFMA GEMM core on packed hi/lo planes, fused column stats ----
__device__ __forceinline__ void gemm_core(
    const unsigned short* __restrict__ Ah, const unsigned short* __restrict__ Al,
    const unsigned short* __restrict__ Wh, const unsigned short* __restrict__ Wl,
    float* __restrict__ Y, float* __restrict__ sums,
    int M, int Ncols, int mtiles, int nblk, int mode, int id)
{
    __shared__ unsigned short As_h[64][40], As_l[64][40], Bs_h[64][40], Bs_l[64][40];
    const int xcd = id & 7;
    const int id8 = id >> 3;
    const int my = xcd + (id8 / nblk) * 8;
    const int ny = id8 % nblk;
    if (my >= mtiles) return;

    const int t = threadIdx.x;
    const int w = t >> 6, lane = t & 63, g = lane >> 4, ln = lane & 15;
    const int m0 = my * 64, n0 = ny * 64;
    const int srow = t >> 2;
    const int sc8 = (t & 3) * 8;

    int mrow = m0 + srow;
    long asrc = -1;
    if (mrow < M) {
        if (mode == 1) {
            int bb = mrow / N_Q;
            int i = mrow - bb * N_Q;
            asrc = (long)(bb * N_K + (i / 42) * 168 + (i % 42) * 2);
        } else asrc = mrow;
    }
    const int nrow = n0 + srow;

    f32x4 acc[4];
    #pragma unroll
    for (int nt = 0; nt < 4; ++nt) acc[nt] = (f32x4){0.f, 0.f, 0.f, 0.f};

    for (int k0 = 0; k0 < 256; k0 += 32) {
        uint4 a_h = make_uint4(0, 0, 0, 0), a_l = a_h;
        if (asrc >= 0) {
            a_h = *(const uint4*)(Ah + asrc * 256 + k0 + sc8);
            a_l = *(const uint4*)(Al + asrc * 256 + k0 + sc8);
        }
        uint4 b_h = *(const uint4*)(Wh + (size_t)nrow * 256 + k0 + sc8);
        uint4 b_l = *(const uint4*)(Wl + (size_t)nrow * 256 + k0 + sc8);

        __syncthreads();
        *(uint4*)&As_h[srow][sc8] = a_h;
        *(uint4*)&As_l[srow][sc8] = a_l;
        *(uint4*)&Bs_h[srow][sc8] = b_h;
        *(uint4*)&Bs_l[srow][sc8] = b_l;
        __syncthreads();

        short8 ah = *(const short8*)&As_h[w * 16 + ln][g * 8];
        short8 al = *(const short8*)&As_l[w * 16 + ln][g * 8];
        #pragma unroll
        for (int nt = 0; nt < 4; ++nt) {
            short8 bh = *(const short8*)&Bs_h[nt * 16 + ln][g * 8];
            short8 bl = *(const short8*)&Bs_l[nt * 16 + ln][g * 8];
            acc[nt] = __builtin_amdgcn_mfma_f32_16x16x32_bf16(al, bh, acc[nt], 0, 0, 0);
            acc[nt] = __builtin_amdgcn_mfma_f32_16x16x32_bf16(ah, bl, acc[nt], 0, 0, 0);
            acc[nt] = __builtin_amdgcn_mfma_f32_16x16x32_bf16(ah, bh, acc[nt], 0, 0, 0);
        }
    }

    #pragma unroll
    for (int nt = 0; nt < 4; ++nt) {
        #pragma unroll
        for (int reg = 0; reg < 4; ++reg) {
            int mr = m0 + w * 16 + g * 4 + reg;
            if (mr < M) Y[(size_t)mr * Ncols + n0 + nt * 16 + ln] = acc[nt][reg];
        }
    }

    float s4[4], q4[4];
    #pragma unroll
    for (int nt = 0; nt < 4; ++nt) {
        float s = acc[nt][0] + acc[nt][1] + acc[nt][2] + acc[nt][3];
        float q = fmaf(acc[nt][0], acc[nt][0], fmaf(acc[nt][1], acc[nt][1],
                  fmaf(acc[nt][2], acc[nt][2], acc[nt][3] * acc[nt][3])));
        s += __shfl_xor(s, 16); s += __shfl_xor(s, 32);
        q += __shfl_xor(q, 16); q += __shfl_xor(q, 32);
        s4[nt] = s; q4[nt] = q;
    }
    __syncthreads();
    float* st_s = (float*)&As_h[0][0];
    float* st_q = st_s + 256;
    if (g == 0) {
        #pragma unroll
        for (int nt = 0; nt < 4; ++nt) {
            st_s[(w * 4 + nt) * 16 + ln] = s4[nt];
            st_q[(w * 4 + nt) * 16 + ln] = q4[nt];
        }
    }
    __syncthreads();
    if (t < 64) {
        int nt = t >> 4, c = t & 15;
        float a = 0.f, b2 = 0.f;
        #pragma unroll
        for (int ww = 0; ww < 4; ++ww) {
            a  += st_s[(ww * 4 + nt) * 16 + c];
            b2 += st_q[(ww * 4 + nt) * 16 + c];
        }
        atomicAdd(&sums[n0 + nt * 16 + c], a);
        atomicAdd(&sums[Ncols + n0 + nt * 16 + c], b2);
    }
}

// ---- fused kv + q GEMM launch ----
__global__ __launch_bounds__(256) void gemm_qkv(
    const unsigned short* __restrict__ Xh, const unsigned short* __restrict__ Xl,
    const unsigned short* __restrict__ Wh, const unsigned short* __restrict__ Wl,
    float* __restrict__ kv_y, float* __restrict__ q_y,
    float* __restrict__ sums_kv, float* __restrict__ sums_q)
{
    int id = blockIdx.x;
    if (id < 1008)
        gemm_core(Xh, Xl, Wh, Wl, kv_y, sums_kv, 10584, 384, 166, 6, 0, id);
    else
        gemm_core(Xh, Xl, Wh + 384 * 256, Wl + 384 * 256, q_y, sums_q,
                  2688, 128, 42, 2, 1, id - 1008);
}

__global__ __launch_bounds__(256) void gemm_proj(
    const unsigned short* __restrict__ Ah, const unsigned short* __restrict__ Al,
    const unsigned short* __restrict__ Wh, const unsigned short* __restrict__ Wl,
    float* __restrict__ Y, float* __restrict__ sums)
{
    gemm_core(Ah, Al, Wh, Wl, Y, sums, 2688, 512, 42, 8, 0, blockIdx.x);
}

// ---- kv_pack: inline BN coeffs + per-head bf16 repack ----
__global__ __launch_bounds__(256) void kv_pack(const float* __restrict__ kv_y,
                                               const float* __restrict__ sums,
                                               const float* __restrict__ kv_g,
                                               const float* __restrict__ kv_b,
                                               unsigned short* __restrict__ Kp,
                                               unsigned short* __restrict__ Vp)
{
    int i = blockIdx.x * 256 + threadIdx.x;
    if (i >= 2 * 8 * N_K * 12) return;
    int c4 = i % 12;
    int key = (i / 12) % N_K;
    int h = (i / (12 * N_K)) & 7;
    int b = i / (12 * N_K * 8);
    int ch = h * 48 + c4 * 4;
    const float inv = 1.f / 10584.f;
    float4 sm = *(const float4*)(sums + ch);
    float4 sq = *(const float4*)(sums + 384 + ch);
    float4 gg = *(const float4*)(kv_g + ch);
    float4 bb = *(const float4*)(kv_b + ch);
    float4 v = *(const float4*)(kv_y + (size_t)(b * N_K + key) * 384 + ch);
    #define BNAPP(c) { float mu = sm.c * inv; \
        float var = fmaf(-mu, mu, sq.c * inv); \
        float s = gg.c * rsqrtf(var + 1e-5f); \
        v.c = fmaf(v.c, s, fmaf(-mu, s, bb.c)); }
    BNAPP(x) BNAPP(y) BNAPP(z) BNAPP(w)
    #undef BNAPP
    uint2 u = make_uint2(pk_bf16(v.x, v.y), pk_bf16(v.z, v.w));
    size_t slot = (size_t)(b * 8 + h) * N_K + key;
    if (c4 < 4) *(uint2*)((unsigned*)Kp + slot * 8 + c4 * 2) = u;
    else        *(uint2*)((unsigned*)Vp + slot * 16 + (c4 - 4) * 2) = u;
}

// ---- MFMA flash attention: static-m softmax, dbuf staging, XCD-pinned ----
// grid 1344: h=id&7 (head->XCD), z=(id>>3)&7 (b*4+ks), qt=id>>6.
// Key-slot permutation s(k)=(k&15)*4+(k>>4) shared by P_s and Vt_s (PV invariant).
__global__ __launch_bounds__(256, 5) void attn_mfma(
    const unsigned short* __restrict__ Kp, const unsigned short* __restrict__ Vp,
    const float* __restrict__ q_y, const float* __restrict__ sums,
    const float* __restrict__ q_g, const float* __restrict__ q_b,
    const float* __restrict__ bt_r,
    float* __restrict__ pl, float* __restrict__ pacc)
{
    const int id = blockIdx.x;
    const int h = id & 7;
    const int z = (id >> 3) & 7;
    const int qt = id >> 6;
    const int b = z >> 2, ks = z & 3;
    const int t = threadIdx.x;
    const int w = t >> 6, lane = t & 63, g = lane >> 4, ln = lane & 15;

    __shared__ float bt_s[21 * 84];            // 7056 B
    __shared__ unsigned short K_s[2][64][24];  // 6144 B (dbuf)
    __shared__ unsigned short Vt_s[2][32][72]; // 9216 B (dbuf)
    __shared__ unsigned short P_s[4][16][72];  // 9216 B (per wave)

    const int q0 = qt * 64;
    const int kstart = ks * 1344;
    const int kend = (kstart + 1344 < N_K) ? kstart + 1344 : N_K;
    const int ntiles = (kend - kstart + 63) >> 6;
    const bool tail = (ks == 3);

    // bias window rows
    const int kr0 = ks * 16;
    const int kr1 = (kend - 1) / 84;
    const int rq2min = (q0 / 42) * 2;
    const int rq2max = ((q0 + 63) / 42) * 2;
    int dr_lo = 0;
    if (rq2min > kr1) dr_lo = rq2min - kr1;
    else if (kr0 > rq2max) dr_lo = kr0 - rq2max;
    int a1 = rq2max - kr0, a2 = kr1 - rq2min;
    int dr_hi = a1 > a2 ? a1 : a2;
    {
        int nb = (dr_hi - dr_lo + 1) * 84;
        const float* src = bt_r + h * N_K + dr_lo * 84;
        for (int j = t; j < nb; j += 256) bt_s[j] = src[j];
    }

    // Q A-fragment with inline BN coeffs (scale 0.25*log2e folded)
    short8 qfrag = (short8)0;
    if (lane < 32) {
        const float inv = 1.f / 2688.f;
        const float post = 0.25f * LOG2E;
        const int c0 = h * 16 + g * 8;
        const float* qp = q_y + (size_t)(b * N_Q + q0 + w * 16 + ln) * NH_KD + c0;
        float vv[8];
        #pragma unroll
        for (int j = 0; j < 8; ++j) {
            float mu  = sums[c0 + j] * inv;
            float var = fmaf(-mu, mu, sums[128 + c0 + j] * inv);
            float s   = q_g[c0 + j] * rsqrtf(var + 1e-5f) * post;
            vv[j] = fmaf(qp[j], s, fmaf(-mu, s, q_b[c0 + j] * post));
        }
        union { short8 s; unsigned u[4]; } qf;
        qf.u[0] = pk_bf16(vv[0], vv[1]); qf.u[1] = pk_bf16(vv[2], vv[3]);
        qf.u[2] = pk_bf16(vv[4], vv[5]); qf.u[3] = pk_bf16(vv[6], vv[7]);
        qfrag = qf.s;
    }

    int rq2[4], cq2[4];
    #pragma unroll
    for (int reg = 0; reg < 4; ++reg) {
        int qg = q0 + w * 16 + g * 4 + reg;
        rq2[reg] = (qg / 42) * 2;
        cq2[reg] = (qg % 42) * 2;
    }
    int kr[4], kc[4];
    #pragma unroll
    for (int st = 0; st < 4; ++st) {
        int kg = kstart + st * 16 + ln;
        kr[st] = kg / 84;
        kc[st] = kg - kr[st] * 84;
    }

    const unsigned* kp_base = (const unsigned*)Kp + (size_t)(b * 8 + h) * N_K * 8;
    const unsigned* vp_base = (const unsigned*)Vp + (size_t)(b * 8 + h) * N_K * 16;
    const int skey = t >> 2, schunk = t & 3;
    const int vslot = ((skey & 15) << 2) | (skey >> 4);
    const int v0 = schunk * 8;

    uint2 kreg; uint4 vreg;
    {
        int kg = kstart + skey; if (kg > N_K - 1) kg = N_K - 1;
        kreg = *(const uint2*)(kp_base + (size_t)kg * 8 + schunk * 2);
        vreg = *(const uint4*)(vp_base + (size_t)kg * 16 + schunk * 4);
    }
    *(uint2*)&K_s[0][skey][schunk * 4] = kreg;
    Vt_s[0][v0 + 0][vslot] = (unsigned short)vreg.x;
    Vt_s[0][v0 + 1][vslot] = (unsigned short)(vreg.x >> 16);
    Vt_s[0][v0 + 2][vslot] = (unsigned short)vreg.y;
    Vt_s[0][v0 + 3][vslot] = (unsigned short)(vreg.y >> 16);
    Vt_s[0][v0 + 4][vslot] = (unsigned short)vreg.z;
    Vt_s[0][v0 + 5][vslot] = (unsigned short)(vreg.z >> 16);
    Vt_s[0][v0 + 6][vslot] = (unsigned short)vreg.w;
    Vt_s[0][v0 + 7][vslot] = (unsigned short)(vreg.w >> 16);
    __syncthreads();

    float l[4] = {0.f, 0.f, 0.f, 0.f};
    f32x4 acc0 = {0.f, 0.f, 0.f, 0.f}, acc1 = {0.f, 0.f, 0.f, 0.f};
    const f32x4 zero4 = {0.f, 0.f, 0.f, 0.f};
    int p = 0;

    for (int it = 0; it < ntiles; ++it) {
        const int k0 = kstart + it * 64;
        const bool notlast = (it + 1 < ntiles);
        if (notlast) {   // issue next-tile global loads early (overlap with compute)
            int kg = k0 + 64 + skey; if (kg > N_K - 1) kg = N_K - 1;
            kreg = *(const uint2*)(kp_base + (size_t)kg * 8 + schunk * 2);
            vreg = *(const uint4*)(vp_base + (size_t)kg * 16 + schunk * 4);
        }

        // QK^T
        f32x4 sf[4];
        #pragma unroll
        for (int st = 0; st < 4; ++st) {
            short8 bf = (short8)0;
            if (lane < 32) bf = *(const short8*)&K_s[p][st * 16 + ln][g * 8];
            sf[st] = __builtin_amdgcn_mfma_f32_16x16x32_bf16(qfrag, bf, zero4, 0, 0, 0);
        }

        // scores: p = exp2(qk + bias')   (static m folded into bias')
        float pv[4][4];
        #pragma unroll
        for (int st = 0; st < 4; ++st) {
            #pragma unroll
            for (int reg = 0; reg < 4; ++reg) {
                int dr = rq2[reg] - kr[st]; dr = dr < 0 ? -dr : dr;
                int dc = cq2[reg] - kc[st]; dc = dc < 0 ? -dc : dc;
                pv[st][reg] = fexp2(sf[st][reg] + bt_s[(dr - dr_lo) * 84 + dc]);
            }
        }
        if (tail && it == ntiles - 1) {   // mask the single partial tile
            #pragma unroll
            for (int st = 0; st < 4; ++st) {
                bool bad = (k0 + st * 16 + ln) >= N_K;
                #pragma unroll
                for (int reg = 0; reg < 4; ++reg)
                    pv[st][reg] = bad ? 0.f : pv[st][reg];
            }
        }

        // l accumulate + P -> LDS (b64 writes via slot permutation)
        #pragma unroll
        for (int reg = 0; reg < 4; ++reg) {
            l[reg] += (pv[0][reg] + pv[1][reg]) + (pv[2][reg] + pv[3][reg]);
            uint2 pw = make_uint2(pk_bf16(pv[0][reg], pv[1][reg]),
                                  pk_bf16(pv[2][reg], pv[3][reg]));
            *(uint2*)&P_s[w][g * 4 + reg][4 * ln] = pw;
        }

        // PV
        #pragma unroll
        for (int kt = 0; kt < 2; ++kt) {
            short8 af = *(const short8*)&P_s[w][ln][g * 8 + kt * 32];
            short8 b0 = *(const short8*)&Vt_s[p][ln][g * 8 + kt * 32];
            short8 b1 = *(const short8*)&Vt_s[p][ln + 16][g * 8 + kt * 32];
            acc0 = __builtin_amdgcn_mfma_f32_16x16x32_bf16(af, b0, acc0, 0, 0, 0);
            acc1 = __builtin_amdgcn_mfma_f32_16x16x32_bf16(af, b1, acc1, 0, 0, 0);
        }

        if (notlast) {   // stage next tile into the other buffer; single barrier
            int q2 = p ^ 1;
            *(uint2*)&K_s[q2][skey][schunk * 4] = kreg;
            Vt_s[q2][v0 + 0][vslot] = (unsigned short)vreg.x;
            Vt_s[q2][v0 + 1][vslot] = (unsigned short)(vreg.x >> 16);
            Vt_s[q2][v0 + 2][vslot] = (unsigned short)vreg.y;
            Vt_s[q2][v0 + 3][vslot] = (unsigned short)(vreg.y >> 16);
            Vt_s[q2][v0 + 4][vslot] = (unsigned short)vreg.z;
            Vt_s[q2][v0 + 5][vslot] = (unsigned short)(vreg.z >> 16);
            Vt_s[q2][v0 + 6][vslot] = (unsigned short)vreg.w;
            Vt_s[q2][v0 + 7][vslot] = (unsigned short)(vreg.w >> 16);
            __syncthreads();
            p = q2;
        }

        #pragma unroll
        for (int st = 0; st < 4; ++st) {
            kc[st] += 64;
            if (kc[st] >= 84) { kc[st] -= 84; kr[st] += 1; }
        }
    }

    #pragma unroll
    for (int reg = 0; reg < 4; ++reg) {
        float s = l[reg];
        s += __shfl_xor(s, 1, 16);
        s += __shfl_xor(s, 2, 16);
        s += __shfl_xor(s, 4, 16);
        s += __shfl_xor(s, 8, 16);
        l[reg] = s;
    }

    const int rbase = (b * 8 + h) * N_Q + q0 + w * 16;
    #pragma unroll
    for (int reg = 0; reg < 4; ++reg) {
        int prow = ks * NROWS + rbase + g * 4 + reg;
        pacc[(size_t)prow * 32 + ln]      = acc0[reg];
        pacc[(size_t)prow * 32 + 16 + ln] = acc1[reg];
        if (ln == 0) pl[prow] = l[reg];
    }
}

// ---- combine 4 key-split partials (plain sums, static m) + hardswish -> hi/lo ----
__global__ __launch_bounds__(256) void combine_kernel(const float* __restrict__ pl,
                                                      const float* __restrict__ pacc,
                                                      unsigned short* __restrict__ oh,
                                                      unsigned short* __restrict__ ol)
{
    int i = blockIdx.x * 256 + threadIdx.x;
    int r = i >> 5, e = i & 31;
    float L = (pl[r] + pl[NROWS + r]) + (pl[2 * NROWS + r] + pl[3 * NROWS + r]);
    float v = (pacc[(size_t)r * 32 + e] + pacc[(size_t)(NROWS + r) * 32 + e])
            + (pacc[(size_t)(2 * NROWS + r) * 32 + e] + pacc[(size_t)(3 * NROWS + r) * 32 + e]);
    v /= L;
    float hs = v * fminf(fmaxf(v + 3.f, 0.f), 6.f) * (1.f / 6.f);
    unsigned hu = pk_bf16(hs, 0.f) & 0xffffu;
    float hf = __uint_as_float(hu << 16);
    unsigned lu = pk_bf16(hs - hf, 0.f) & 0xffffu;
    int q = r % N_Q;
    int bh = r / N_Q;
    int hh = bh & 7, b = bh >> 3;
    size_t idx = (size_t)(b * N_Q + q) * 256 + hh * 32 + e;
    oh[idx] = (unsigned short)hu;
    ol[idx] = (unsigned short)lu;
}

// ---- final BN apply ----
__global__ __launch_bounds__(256) void norm_apply(
    const float* __restrict__ Y, const float* __restrict__ sums,
    const float* __restrict__ g, const float* __restrict__ bb,
    float* __restrict__ out, int rows, int cols, float inv_rows)
{
    __shared__ float sc_s[64], sh_s[64];
    const int t = threadIdx.x;
    const int c0 = blockIdx.x * 64;
    if (t < 64) {
        int c = c0 + t;
        float mu  = sums[c] * inv_rows;
        float var = fmaf(-mu, mu, sums[cols + c] * inv_rows);
        float s   = g[c] * rsqrtf(var + 1e-5f);
        sc_s[t] = s;
        sh_s[t] = fmaf(-mu, s, bb[c]);
    }
    __syncthreads();
    const int c4 = (t & 15) * 4;
    float4 scv = *(const float4*)&sc_s[c4];
    float4 shv = *(const float4*)&sh_s[c4];
    for (int r = blockIdx.y * 16 + (t >> 4); r < rows; r += gridDim.y * 16) {
        size_t off = (size_t)r * cols + c0 + c4;
        float4 v = *(const float4*)(Y + off);
        v.x = fmaf(v.x, scv.x, shv.x);
        v.y = fmaf(v.y, scv.y, shv.y);
        v.z = fmaf(v.z, scv.z, shv.z);
        v.w = fmaf(v.w, scv.w, shv.w);
        *(float4*)(out + off) = v;
    }
}

extern "C" void kernel_launch(void* const* d_in, const int* in_sizes, int n_in,
                              void* d_out, int out_size, void* d_ws, size_t ws_size,
                              hipStream_t stream) {
    (void)n_in; (void)out_size; (void)ws_size;
    const float* x      = (const float*)d_in[0];
    const float* kv_w   = (const float*)d_in[1];
    const float* kv_g   = (const float*)d_in[2];
    const float* kv_b   = (const float*)d_in[3];
    const float* q_w    = (const float*)d_in[4];
    const float* q_g    = (const float*)d_in[5];
    const float* q_b    = (const float*)d_in[6];
    const float* proj_w = (const float*)d_in[7];
    const float* proj_g = (const float*)d_in[8];
    const float* proj_b = (const float*)d_in[9];
    const float* bias_table = (const float*)d_in[10];
    const int*   bias_idxs  = (const int*)d_in[11];
    const int    n_off = in_sizes[10] / 8;
    float* out = (float*)d_out;

    float* ws = (float*)d_ws;
    float* kv_y = ws;                                    // 4,064,256
    float* q_y  = kv_y + 10584 * 384;                    // 344,064
    float* regA = q_y + 2688 * 128;                      // 2,752,512: Xh/Xl -> pacc -> proj_y
    unsigned short* Xh = (unsigned short*)regA;          // 10584*256 u16
    unsigned short* Xl = Xh + 10584 * 256;
    float* pacc   = regA;
    float* proj_y = regA;
    float* pl = regA + 4 * NROWS * 32;                   // 86,016
    unsigned short* Wh = (unsigned short*)(pl + 4 * NROWS);  // 1024*256 u16
    unsigned short* Wl = Wh + 1024 * 256;
    unsigned short* attn_oh = Wl + 1024 * 256;           // 2688*256 u16 each
    unsigned short* attn_ol = attn_oh + 2688 * 256;
    unsigned short* Kp = attn_ol + 2688 * 256;           // 2*8*5292*16 u16
    unsigned short* Vp = Kp + 2 * 8 * N_K * 16;          // 2*8*5292*32 u16
    float* sums_kv = (float*)(Vp + 2 * 8 * N_K * 32);    // 768
    float* sums_q  = sums_kv + 768;                      // 256
    float* sums_p  = sums_q + 256;                       // 1024
    float* bt_r    = sums_p + 1024;                      // 8*5292

    // 1) prep: zero stats + pack X/W + bias remap
    prep_kernel<<<3076, 256, 0, stream>>>(x, kv_w, q_w, proj_w, bias_table, bias_idxs,
                                          n_off, sums_kv, Xh, Xl, Wh, Wl, bt_r);
    // 2) kv + q GEMMs (fused, XCD-swizzled)
    gemm_qkv<<<1104, 256, 0, stream>>>(Xh, Xl, Wh, Wl, kv_y, q_y, sums_kv, sums_q);
    // 3) BN + per-head bf16 repack of K/V (coeffs inline)
    kv_pack<<<3969, 256, 0, stream>>>(kv_y, sums_kv, kv_g, kv_b, Kp, Vp);
    // 4) flash attention (static-m, dbuf, XCD-pinned)
    attn_mfma<<<1344, 256, 0, stream>>>(Kp, Vp, q_y, sums_q, q_g, q_b, bt_r, pl, pacc);
    // 5) combine + hardswish -> hi/lo planes
    combine_kernel<<<2688, 256, 0, stream>>>(pl, pacc, attn_oh, attn_ol);
    // 6) proj GEMM
    gemm_proj<<<384, 256, 0, stream>>>(attn_oh, attn_ol, Wh + 512 * 256, Wl + 512 * 256,
                                       proj_y, sums_p);
    // 7) final BN -> out
    norm_apply<<<dim3(8, 84), 256, 0, stream>>>(proj_y, sums_p, proj_g, proj_b, out,
                                                2688, 512, 1.f / 2688.f);
}

// Round 7
// 210.581 us; speedup vs baseline: 1.5286x; 1.0548x over previous
//
#include <hip/hip_runtime.h>
#include <hip/hip_bf16.h>
#include <math.h>

#define N_K 5292
#define N_Q 1344
#define NH_KD 128
#define NROWS 21504   // 2*8*1344 (b,h,q) rows of partials
#define LOG2E 1.4426950408889634f
#define MSTAT 16.0f   // static softmax shift (log2 domain), folded into bias

typedef float f32x4 __attribute__((ext_vector_type(4)));
typedef short short8 __attribute__((ext_vector_type(8)));

__device__ __forceinline__ float fexp2(float x) {
#if __has_builtin(__builtin_amdgcn_exp2f)
    return __builtin_amdgcn_exp2f(x);
#else
    return exp2f(x);
#endif
}

// packed f32x2 -> bf16x2 (v_cvt_pk_bf16_f32); a in low 16 bits
__device__ __forceinline__ unsigned pk_bf16(float a, float b) {
    union { __hip_bfloat162 h; unsigned u; } c;
    c.h = __float22bfloat162_rn(make_float2(a, b));
    return c.u;
}
__device__ __forceinline__ unsigned short f2bf(float a) {
    return (unsigned short)pk_bf16(a, 0.f);
}

// ---- fused prep: zero stats | pack X bf16 | pack W bf16 | bias remap ----
__global__ __launch_bounds__(256) void prep_kernel(
    const float* __restrict__ x, const float* __restrict__ kv_w,
    const float* __restrict__ q_w, const float* __restrict__ proj_w,
    const float* __restrict__ bias_table, const int* __restrict__ bias_idxs, int n_off,
    float* __restrict__ sums, unsigned short* __restrict__ Xp,
    unsigned short* __restrict__ Wp, float* __restrict__ bt_r)
{
    int bid = blockIdx.x;
    const int t = threadIdx.x;
    if (bid < 8) {                                  // zero 2048 stats floats
        int i = bid * 256 + t;
        if (i < 2048) sums[i] = 0.f;
        return;
    }
    bid -= 8;
    if (bid < 2646) {                               // pack X (677376 float4 groups)
        int i = bid * 256 + t;
        float4 v = ((const float4*)x)[i];
        ((uint2*)Xp)[i] = make_uint2(pk_bf16(v.x, v.y), pk_bf16(v.z, v.w));
        return;
    }
    bid -= 2646;
    if (bid < 256) {                                // pack W (kv|q|proj concat, 65536 groups)
        int i = bid * 256 + t;
        int j = i;
        const float* s;
        if (j < 384 * 64) s = kv_w;
        else if ((j -= 384 * 64) < 128 * 64) s = q_w;
        else { j -= 128 * 64; s = proj_w; }
        float4 v = ((const float4*)s)[j];
        ((uint2*)Wp)[i] = make_uint2(pk_bf16(v.x, v.y), pk_bf16(v.z, v.w));
        return;
    }
    bid -= 256;
    {                                               // bias remap (log2e, -MSTAT folded)
        int i = bid * 256 + t;
        if (i < 8 * N_K) {
            int h = i / N_K, j = i - h * N_K;
            bt_r[i] = fmaf(bias_table[h * n_off + bias_idxs[j]], LOG2E, -MSTAT);
        }
    }
}

// ---- shared GEMM tile body: acc[nt] = A(m0+..,:) . W(n0+..,:)^T, K=256, bf16 ----
__device__ __forceinline__ void gemm_body(
    const unsigned short* __restrict__ Ap, const unsigned short* __restrict__ Wp,
    long asrc, int nrow,
    unsigned short (*As)[40], unsigned short (*Bs)[40], f32x4 acc[4])
{
    const int t = threadIdx.x;
    const int w = t >> 6, lane = t & 63, g = lane >> 4, ln = lane & 15;
    const int srow = t >> 2;
    const int sc8 = (t & 3) * 8;

    for (int k0 = 0; k0 < 256; k0 += 32) {
        uint4 a = make_uint4(0, 0, 0, 0);
        if (asrc >= 0) a = *(const uint4*)(Ap + asrc * 256 + k0 + sc8);
        uint4 b = *(const uint4*)(Wp + (size_t)nrow * 256 + k0 + sc8);

        __syncthreads();
        *(uint4*)&As[srow][sc8] = a;
        *(uint4*)&Bs[srow][sc8] = b;
        __syncthreads();

        short8 ah = *(const short8*)&As[w * 16 + ln][g * 8];
        #pragma unroll
        for (int nt = 0; nt < 4; ++nt) {
            short8 bh = *(const short8*)&Bs[nt * 16 + ln][g * 8];
            acc[nt] = __builtin_amdgcn_mfma_f32_16x16x32_bf16(ah, bh, acc[nt], 0, 0, 0);
        }
    }
}

// ---- shared fused column stats (sum/sumsq of this block's 64 rows) ----
__device__ __forceinline__ void gemm_stats(f32x4 acc[4], float* __restrict__ sums,
                                           int n0, int Ncols, float* scratch)
{
    const int t = threadIdx.x;
    const int w = t >> 6, lane = t & 63, g = lane >> 4, ln = lane & 15;
    float s4[4], q4[4];
    #pragma unroll
    for (int nt = 0; nt < 4; ++nt) {
        float s = acc[nt][0] + acc[nt][1] + acc[nt][2] + acc[nt][3];
        float q = fmaf(acc[nt][0], acc[nt][0], fmaf(acc[nt][1], acc[nt][1],
                  fmaf(acc[nt][2], acc[nt][2], acc[nt][3] * acc[nt][3])));
        s += __shfl_xor(s, 16); s += __shfl_xor(s, 32);
        q += __shfl_xor(q, 16); q += __shfl_xor(q, 32);
        s4[nt] = s; q4[nt] = q;
    }
    __syncthreads();
    float* st_s = scratch;
    float* st_q = scratch + 256;
    if (g == 0) {
        #pragma unroll
        for (int nt = 0; nt < 4; ++nt) {
            st_s[(w * 4 + nt) * 16 + ln] = s4[nt];
            st_q[(w * 4 + nt) * 16 + ln] = q4[nt];
        }
    }
    __syncthreads();
    if (t < 64) {
        int nt = t >> 4, c = t & 15;
        float a = 0.f, b2 = 0.f;
        #pragma unroll
        for (int ww = 0; ww < 4; ++ww) {
            a  += st_s[(ww * 4 + nt) * 16 + c];
            b2 += st_q[(ww * 4 + nt) * 16 + c];
        }
        atomicAdd(&sums[n0 + nt * 16 + c], a);
        atomicAdd(&sums[Ncols + n0 + nt * 16 + c], b2);
    }
}

// ---- kv + q GEMMs. kv epilogue writes RAW bf16 K/V in per-head packed layout
// (BN folded downstream: K-scale into Q, K-shift cancels in softmax, V-BN in combine).
__global__ __launch_bounds__(256) void gemm_qkv(
    const unsigned short* __restrict__ Xp, const unsigned short* __restrict__ Wp,
    unsigned short* __restrict__ Kp, unsigned short* __restrict__ Vp,
    float* __restrict__ q_y, float* __restrict__ sums_kv, float* __restrict__ sums_q)
{
    __shared__ unsigned short As[64][40], Bs[64][40];
    const int t = threadIdx.x;
    const int w = t >> 6, lane = t & 63, g = lane >> 4, ln = lane & 15;
    const int srow = t >> 2;
    int id = blockIdx.x;

    f32x4 acc[4];
    #pragma unroll
    for (int nt = 0; nt < 4; ++nt) acc[nt] = (f32x4){0.f, 0.f, 0.f, 0.f};

    if (id < 1008) {            // kv: mtiles=166, nblk=6
        const int xcd = id & 7, id8 = id >> 3;
        const int my = xcd + (id8 / 6) * 8, ny = id8 % 6;
        if (my >= 166) return;
        const int m0 = my * 64, n0 = ny * 64;
        int mrow = m0 + srow;
        long asrc = (mrow < 10584) ? mrow : -1;
        gemm_body(Xp, Wp, asrc, n0 + srow, As, Bs, acc);

        #pragma unroll
        for (int nt = 0; nt < 4; ++nt) {
            int c = n0 + nt * 16 + ln;
            int hh = c / 48, cc = c - 48 * hh;
            #pragma unroll
            for (int reg = 0; reg < 4; ++reg) {
                int mr = m0 + w * 16 + g * 4 + reg;
                if (mr < 10584) {
                    int bb = mr >= N_K;
                    int key = mr - bb * N_K;
                    unsigned short v16 = f2bf(acc[nt][reg]);
                    size_t slot = (size_t)(bb * 8 + hh) * N_K + key;
                    if (cc < 16) Kp[slot * 16 + cc] = v16;
                    else         Vp[slot * 32 + cc - 16] = v16;
                }
            }
        }
        gemm_stats(acc, sums_kv, n0, 384, (float*)&As[0][0]);
    } else {                    // q: mtiles=42, nblk=2 (strided subsample rows)
        id -= 1008;
        const int xcd = id & 7, id8 = id >> 3;
        const int my = xcd + (id8 / 2) * 8, ny = id8 % 2;
        if (my >= 42) return;
        const int m0 = my * 64, n0 = ny * 64;
        int mrow = m0 + srow;
        long asrc = -1;
        {
            int bb = mrow / N_Q;
            int i = mrow - bb * N_Q;
            asrc = (long)(bb * N_K + (i / 42) * 168 + (i % 42) * 2);
        }
        gemm_body(Xp, Wp + 384 * 256, asrc, n0 + srow, As, Bs, acc);

        #pragma unroll
        for (int nt = 0; nt < 4; ++nt)
            #pragma unroll
            for (int reg = 0; reg < 4; ++reg) {
                int mr = m0 + w * 16 + g * 4 + reg;
                q_y[(size_t)mr * 128 + n0 + nt * 16 + ln] = acc[nt][reg];
            }
        gemm_stats(acc, sums_q, n0, 128, (float*)&As[0][0]);
    }
}

// ---- proj GEMM (A = bf16 attn_o plane) ----
__global__ __launch_bounds__(256) void gemm_proj(
    const unsigned short* __restrict__ Ap, const unsigned short* __restrict__ Wp,
    float* __restrict__ Y, float* __restrict__ sums)
{
    __shared__ unsigned short As[64][40], Bs[64][40];
    const int t = threadIdx.x;
    const int w = t >> 6, lane = t & 63, g = lane >> 4, ln = lane & 15;
    const int id = blockIdx.x;
    const int xcd = id & 7, id8 = id >> 3;
    const int my = xcd + (id8 / 8) * 8, ny = id8 % 8;
    if (my >= 42) return;
    const int m0 = my * 64, n0 = ny * 64;

    f32x4 acc[4];
    #pragma unroll
    for (int nt = 0; nt < 4; ++nt) acc[nt] = (f32x4){0.f, 0.f, 0.f, 0.f};
    gemm_body(Ap, Wp, m0 + (t >> 2), n0 + (t >> 2), As, Bs, acc);

    #pragma unroll
    for (int nt = 0; nt < 4; ++nt)
        #pragma unroll
        for (int reg = 0; reg < 4; ++reg) {
            int mr = m0 + w * 16 + g * 4 + reg;
            Y[(size_t)mr * 512 + n0 + nt * 16 + ln] = acc[nt][reg];
        }
    gemm_stats(acc, sums, n0, 512, (float*)&As[0][0]);
}

// ---- MFMA flash attention: static-m softmax, dbuf staging, XCD-pinned,
// raw K with BN-scale folded into Q (shift cancels in softmax) ----
__global__ __launch_bounds__(256, 5) void attn_mfma(
    const unsigned short* __restrict__ Kp, const unsigned short* __restrict__ Vp,
    const float* __restrict__ q_y, const float* __restrict__ sums_q,
    const float* __restrict__ q_g, const float* __restrict__ q_b,
    const float* __restrict__ sums_kv, const float* __restrict__ kv_g,
    const float* __restrict__ bt_r,
    float* __restrict__ pl, float* __restrict__ pacc)
{
    const int id = blockIdx.x;
    const int h = id & 7;
    const int z = (id >> 3) & 7;
    const int qt = id >> 6;
    const int b = z >> 2, ks = z & 3;
    const int t = threadIdx.x;
    const int w = t >> 6, lane = t & 63, g = lane >> 4, ln = lane & 15;

    __shared__ float bt_s[21 * 84];            // 7056 B
    __shared__ unsigned short K_s[2][64][24];  // 6144 B (dbuf)
    __shared__ unsigned short Vt_s[2][32][72]; // 9216 B (dbuf)
    __shared__ unsigned short P_s[4][16][72];  // 9216 B (per wave)

    const int q0 = qt * 64;
    const int kstart = ks * 1344;
    const int kend = (kstart + 1344 < N_K) ? kstart + 1344 : N_K;
    const int ntiles = (kend - kstart + 63) >> 6;
    const bool tail = (ks == 3);

    // bias window rows
    const int kr0 = ks * 16;
    const int kr1 = (kend - 1) / 84;
    const int rq2min = (q0 / 42) * 2;
    const int rq2max = ((q0 + 63) / 42) * 2;
    int dr_lo = 0;
    if (rq2min > kr1) dr_lo = rq2min - kr1;
    else if (kr0 > rq2max) dr_lo = kr0 - rq2max;
    int a1 = rq2max - kr0, a2 = kr1 - rq2min;
    int dr_hi = a1 > a2 ? a1 : a2;
    {
        int nb = (dr_hi - dr_lo + 1) * 84;
        const float* src = bt_r + h * N_K + dr_lo * 84;
        for (int j = t; j < nb; j += 256) bt_s[j] = src[j];
    }

    // Q A-fragment: q-BN (0.25*log2e folded) times K-channel BN scale
    short8 qfrag = (short8)0;
    if (lane < 32) {
        const float invq = 1.f / 2688.f, invk = 1.f / 10584.f;
        const float post = 0.25f * LOG2E;
        const int c0 = h * 16 + g * 8;        // q channels
        const int ck = h * 48 + g * 8;        // kv K channels (g<2 -> 0..15)
        const float* qp = q_y + (size_t)(b * N_Q + q0 + w * 16 + ln) * NH_KD + c0;
        float vv[8];
        #pragma unroll
        for (int j = 0; j < 8; ++j) {
            float mu  = sums_q[c0 + j] * invq;
            float var = fmaf(-mu, mu, sums_q[128 + c0 + j] * invq);
            float s   = q_g[c0 + j] * rsqrtf(var + 1e-5f) * post;
            float vq  = fmaf(qp[j], s, fmaf(-mu, s, q_b[c0 + j] * post));
            float muk = sums_kv[ck + j] * invk;
            float vrk = fmaf(-muk, muk, sums_kv[384 + ck + j] * invk);
            float sk  = kv_g[ck + j] * rsqrtf(vrk + 1e-5f);
            vv[j] = vq * sk;
        }
        union { short8 s; unsigned u[4]; } qf;
        qf.u[0] = pk_bf16(vv[0], vv[1]); qf.u[1] = pk_bf16(vv[2], vv[3]);
        qf.u[2] = pk_bf16(vv[4], vv[5]); qf.u[3] = pk_bf16(vv[6], vv[7]);
        qfrag = qf.s;
    }

    int rq2[4], cq2[4];
    #pragma unroll
    for (int reg = 0; reg < 4; ++reg) {
        int qg = q0 + w * 16 + g * 4 + reg;
        rq2[reg] = (qg / 42) * 2;
        cq2[reg] = (qg % 42) * 2;
    }
    int kr[4], kc[4];
    #pragma unroll
    for (int st = 0; st < 4; ++st) {
        int kg = kstart + st * 16 + ln;
        kr[st] = kg / 84;
        kc[st] = kg - kr[st] * 84;
    }

    const unsigned* kp_base = (const unsigned*)Kp + (size_t)(b * 8 + h) * N_K * 8;
    const unsigned* vp_base = (const unsigned*)Vp + (size_t)(b * 8 + h) * N_K * 16;
    const int skey = t >> 2, schunk = t & 3;
    const int vslot = ((skey & 15) << 2) | (skey >> 4);
    const int v0 = schunk * 8;

    uint2 kreg; uint4 vreg;
    {
        int kg = kstart + skey; if (kg > N_K - 1) kg = N_K - 1;
        kreg = *(const uint2*)(kp_base + (size_t)kg * 8 + schunk * 2);
        vreg = *(const uint4*)(vp_base + (size_t)kg * 16 + schunk * 4);
    }
    *(uint2*)&K_s[0][skey][schunk * 4] = kreg;
    Vt_s[0][v0 + 0][vslot] = (unsigned short)vreg.x;
    Vt_s[0][v0 + 1][vslot] = (unsigned short)(vreg.x >> 16);
    Vt_s[0][v0 + 2][vslot] = (unsigned short)vreg.y;
    Vt_s[0][v0 + 3][vslot] = (unsigned short)(vreg.y >> 16);
    Vt_s[0][v0 + 4][vslot] = (unsigned short)vreg.z;
    Vt_s[0][v0 + 5][vslot] = (unsigned short)(vreg.z >> 16);
    Vt_s[0][v0 + 6][vslot] = (unsigned short)vreg.w;
    Vt_s[0][v0 + 7][vslot] = (unsigned short)(vreg.w >> 16);
    __syncthreads();

    float l[4] = {0.f, 0.f, 0.f, 0.f};
    f32x4 acc0 = {0.f, 0.f, 0.f, 0.f}, acc1 = {0.f, 0.f, 0.f, 0.f};
    const f32x4 zero4 = {0.f, 0.f, 0.f, 0.f};
    int p = 0;

    for (int it = 0; it < ntiles; ++it) {
        const int k0 = kstart + it * 64;
        const bool notlast = (it + 1 < ntiles);
        if (notlast) {   // issue next-tile global loads early
            int kg = k0 + 64 + skey; if (kg > N_K - 1) kg = N_K - 1;
            kreg = *(const uint2*)(kp_base + (size_t)kg * 8 + schunk * 2);
            vreg = *(const uint4*)(vp_base + (size_t)kg * 16 + schunk * 4);
        }

        // QK^T
        f32x4 sf[4];
        #pragma unroll
        for (int st = 0; st < 4; ++st) {
            short8 bf = (short8)0;
            if (lane < 32) bf = *(const short8*)&K_s[p][st * 16 + ln][g * 8];
            sf[st] = __builtin_amdgcn_mfma_f32_16x16x32_bf16(qfrag, bf, zero4, 0, 0, 0);
        }

        // p = exp2(qk + bias')  (static m folded into bias')
        float pv[4][4];
        #pragma unroll
        for (int st = 0; st < 4; ++st) {
            #pragma unroll
            for (int reg = 0; reg < 4; ++reg) {
                int dr = rq2[reg] - kr[st]; dr = dr < 0 ? -dr : dr;
                int dc = cq2[reg] - kc[st]; dc = dc < 0 ? -dc : dc;
                pv[st][reg] = fexp2(sf[st][reg] + bt_s[(dr - dr_lo) * 84 + dc]);
            }
        }
        if (tail && it == ntiles - 1) {
            #pragma unroll
            for (int st = 0; st < 4; ++st) {
                bool bad = (k0 + st * 16 + ln) >= N_K;
                #pragma unroll
                for (int reg = 0; reg < 4; ++reg)
                    pv[st][reg] = bad ? 0.f : pv[st][reg];
            }
        }

        // l accumulate + P -> LDS (b64 writes via slot permutation)
        #pragma unroll
        for (int reg = 0; reg < 4; ++reg) {
            l[reg] += (pv[0][reg] + pv[1][reg]) + (pv[2][reg] + pv[3][reg]);
            uint2 pw = make_uint2(pk_bf16(pv[0][reg], pv[1][reg]),
                                  pk_bf16(pv[2][reg], pv[3][reg]));
            *(uint2*)&P_s[w][g * 4 + reg][4 * ln] = pw;
        }

        // PV
        #pragma unroll
        for (int kt = 0; kt < 2; ++kt) {
            short8 af = *(const short8*)&P_s[w][ln][g * 8 + kt * 32];
            short8 b0 = *(const short8*)&Vt_s[p][ln][g * 8 + kt * 32];
            short8 b1 = *(const short8*)&Vt_s[p][ln + 16][g * 8 + kt * 32];
            acc0 = __builtin_amdgcn_mfma_f32_16x16x32_bf16(af, b0, acc0, 0, 0, 0);
            acc1 = __builtin_amdgcn_mfma_f32_16x16x32_bf16(af, b1, acc1, 0, 0, 0);
        }

        if (notlast) {
            int q2 = p ^ 1;
            *(uint2*)&K_s[q2][skey][schunk * 4] = kreg;
            Vt_s[q2][v0 + 0][vslot] = (unsigned short)vreg.x;
            Vt_s[q2][v0 + 1][vslot] = (unsigned short)(vreg.x >> 16);
            Vt_s[q2][v0 + 2][vslot] = (unsigned short)vreg.y;
            Vt_s[q2][v0 + 3][vslot] = (unsigned short)(vreg.y >> 16);
            Vt_s[q2][v0 + 4][vslot] = (unsigned short)vreg.z;
            Vt_s[q2][v0 + 5][vslot] = (unsigned short)(vreg.z >> 16);
            Vt_s[q2][v0 + 6][vslot] = (unsigned short)vreg.w;
            Vt_s[q2][v0 + 7][vslot] = (unsigned short)(vreg.w >> 16);
            __syncthreads();
            p = q2;
        }

        #pragma unroll
        for (int st = 0; st < 4; ++st) {
            kc[st] += 64;
            if (kc[st] >= 84) { kc[st] -= 84; kr[st] += 1; }
        }
    }

    #pragma unroll
    for (int reg = 0; reg < 4; ++reg) {
        float s = l[reg];
        s += __shfl_xor(s, 1, 16);
        s += __shfl_xor(s, 2, 16);
        s += __shfl_xor(s, 4, 16);
        s += __shfl_xor(s, 8, 16);
        l[reg] = s;
    }

    const int rbase = (b * 8 + h) * N_Q + q0 + w * 16;
    #pragma unroll
    for (int reg = 0; reg < 4; ++reg) {
        int prow = ks * NROWS + rbase + g * 4 + reg;
        pacc[(size_t)prow * 32 + ln]      = acc0[reg];
        pacc[(size_t)prow * 32 + 16 + ln] = acc1[reg];
        if (ln == 0) pl[prow] = l[reg];
    }
}

// ---- combine partials + V-BN (folded) + hardswish -> bf16 plane ----
__global__ __launch_bounds__(256) void combine_kernel(const float* __restrict__ pl,
                                                      const float* __restrict__ pacc,
                                                      const float* __restrict__ sums_kv,
                                                      const float* __restrict__ kv_g,
                                                      const float* __restrict__ kv_b,
                                                      unsigned short* __restrict__ attn_o)
{
    int i = blockIdx.x * 256 + threadIdx.x;
    int r = i >> 5, e = i & 31;
    float L = (pl[r] + pl[NROWS + r]) + (pl[2 * NROWS + r] + pl[3 * NROWS + r]);
    float v = (pacc[(size_t)r * 32 + e] + pacc[(size_t)(NROWS + r) * 32 + e])
            + (pacc[(size_t)(2 * NROWS + r) * 32 + e] + pacc[(size_t)(3 * NROWS + r) * 32 + e]);
    int q = r % N_Q;
    int bh = r / N_Q;
    int hh = bh & 7, b = bh >> 3;
    // V BN (deferred): v_bn = s*(acc/L) + t
    const int ch = hh * 48 + 16 + e;
    const float invk = 1.f / 10584.f;
    float mu  = sums_kv[ch] * invk;
    float var = fmaf(-mu, mu, sums_kv[384 + ch] * invk);
    float s   = kv_g[ch] * rsqrtf(var + 1e-5f);
    float tt  = fmaf(-mu, s, kv_b[ch]);
    v = fmaf(s, v / L, tt);
    float hs = v * fminf(fmaxf(v + 3.f, 0.f), 6.f) * (1.f / 6.f);
    attn_o[(size_t)(b * N_Q + q) * 256 + hh * 32 + e] = f2bf(hs);
}

// ---- final BN apply ----
__global__ __launch_bounds__(256) void norm_apply(
    const float* __restrict__ Y, const float* __restrict__ sums,
    const float* __restrict__ g, const float* __restrict__ bb,
    float* __restrict__ out, int rows, int cols, float inv_rows)
{
    __shared__ float sc_s[64], sh_s[64];
    const int t = threadIdx.x;
    const int c0 = blockIdx.x * 64;
    if (t < 64) {
        int c = c0 + t;
        float mu  = sums[c] * inv_rows;
        float var = fmaf(-mu, mu, sums[cols + c] * inv_rows);
        float s   = g[c] * rsqrtf(var + 1e-5f);
        sc_s[t] = s;
        sh_s[t] = fmaf(-mu, s, bb[c]);
    }
    __syncthreads();
    const int c4 = (t & 15) * 4;
    float4 scv = *(const float4*)&sc_s[c4];
    float4 shv = *(const float4*)&sh_s[c4];
    for (int r = blockIdx.y * 16 + (t >> 4); r < rows; r += gridDim.y * 16) {
        size_t off = (size_t)r * cols + c0 + c4;
        float4 v = *(const float4*)(Y + off);
        v.x = fmaf(v.x, scv.x, shv.x);
        v.y = fmaf(v.y, scv.y, shv.y);
        v.z = fmaf(v.z, scv.z, shv.z);
        v.w = fmaf(v.w, scv.w, shv.w);
        *(float4*)(out + off) = v;
    }
}

extern "C" void kernel_launch(void* const* d_in, const int* in_sizes, int n_in,
                              void* d_out, int out_size, void* d_ws, size_t ws_size,
                              hipStream_t stream) {
    (void)n_in; (void)out_size; (void)ws_size;
    const float* x      = (const float*)d_in[0];
    const float* kv_w   = (const float*)d_in[1];
    const float* kv_g   = (const float*)d_in[2];
    const float* kv_b   = (const float*)d_in[3];
    const float* q_w    = (const float*)d_in[4];
    const float* q_g    = (const float*)d_in[5];
    const float* q_b    = (const float*)d_in[6];
    const float* proj_w = (const float*)d_in[7];
    const float* proj_g = (const float*)d_in[8];
    const float* proj_b = (const float*)d_in[9];
    const float* bias_table = (const float*)d_in[10];
    const int*   bias_idxs  = (const int*)d_in[11];
    const int    n_off = in_sizes[10] / 8;
    float* out = (float*)d_out;

    float* ws = (float*)d_ws;
    float* q_y  = ws;                                   // 344,064
    float* pacc = q_y + 2688 * 128;                     // 2,752,512 (overlay proj_y)
    float* proj_y = pacc;
    float* pl = pacc + 4 * NROWS * 32;                  // 86,016
    unsigned short* Xp = (unsigned short*)(pl + 4 * NROWS);   // 10584*256 u16
    unsigned short* Wp = Xp + 10584 * 256;              // 1024*256 u16
    unsigned short* attn_o = Wp + 1024 * 256;           // 2688*256 u16
    unsigned short* Kp = attn_o + 2688 * 256;           // 2*8*5292*16 u16
    unsigned short* Vp = Kp + 2 * 8 * N_K * 16;         // 2*8*5292*32 u16
    float* sums_kv = (float*)(Vp + 2 * 8 * N_K * 32);   // 768
    float* sums_q  = sums_kv + 768;                     // 256
    float* sums_p  = sums_q + 256;                      // 1024
    float* bt_r    = sums_p + 1024;                     // 8*5292

    // 1) prep: zero stats + pack X/W (bf16) + bias remap
    prep_kernel<<<3076, 256, 0, stream>>>(x, kv_w, q_w, proj_w, bias_table, bias_idxs,
                                          n_off, sums_kv, Xp, Wp, bt_r);
    // 2) kv + q GEMMs: kv writes raw bf16 Kp/Vp directly (BN folded downstream)
    gemm_qkv<<<1104, 256, 0, stream>>>(Xp, Wp, Kp, Vp, q_y, sums_kv, sums_q);
    // 3) flash attention (static-m, dbuf, XCD-pinned; K-scale folded into Q)
    attn_mfma<<<1344, 256, 0, stream>>>(Kp, Vp, q_y, sums_q, q_g, q_b,
                                        sums_kv, kv_g, bt_r, pl, pacc);
    // 4) combine + V-BN + hardswish -> bf16 plane
    combine_kernel<<<2688, 256, 0, stream>>>(pl, pacc, sums_kv, kv_g, kv_b, attn_o);
    // 5) proj GEMM
    gemm_proj<<<8 * 6 * 8, 256, 0, stream>>>(attn_o, Wp + 512 * 256, proj_y, sums_p);
    // 6) final BN -> out
    norm_apply<<<dim3(8, 84), 256, 0, stream>>>(proj_y, sums_p, proj_g, proj_b, out,
                                                2688, 512, 1.f / 2688.f);
}